// Round 1
// baseline (582.768 us; speedup 1.0000x reference)
//
#include <hip/hip_runtime.h>
#include <cstdint>

#define Bn 128
#define Nn 4096
#define Dn 64
#define Kn 8
#define PBn 4
#define NCHUNKn (Nn / PBn)
#define LN_EPSf 1e-5f
#define EPSf 1e-8f
#define SCALE_INVf 0.125f

typedef short bf16x8 __attribute__((ext_vector_type(8)));
typedef float f32x4 __attribute__((ext_vector_type(4)));
typedef unsigned short u16x4 __attribute__((ext_vector_type(4)));
typedef unsigned short u16x8 __attribute__((ext_vector_type(8)));

static __device__ __forceinline__ uint16_t f2bf(float f) {
    union { float f; uint32_t u; } v; v.f = f;
    return (uint16_t)((v.u + 0x7fffu + ((v.u >> 16) & 1u)) >> 16);
}
static __device__ __forceinline__ float bflo(uint32_t u) {
    union { uint32_t u; float f; } v; v.u = u << 16; return v.f;
}
static __device__ __forceinline__ float bfhi(uint32_t u) {
    union { uint32_t u; float f; } v; v.u = u & 0xffff0000u; return v.f;
}

// ---------------- slot init: slots = mu + exp(ls)*noise ----------------
__global__ __launch_bounds__(256) void kinit(const float* __restrict__ noise,
                                             const float* __restrict__ mu,
                                             const float* __restrict__ ls,
                                             float* __restrict__ slots) {
    int i = blockIdx.x * 256 + threadIdx.x;
    int base = i * 4;
    int d = base & 63;
    float4 nz = *(const float4*)(noise + base);
    float4 m  = *(const float4*)(mu + d);
    float4 s  = *(const float4*)(ls + d);
    float4 o;
    o.x = m.x + __expf(s.x) * nz.x;
    o.y = m.y + __expf(s.y) * nz.y;
    o.z = m.z + __expf(s.z) * nz.z;
    o.w = m.w + __expf(s.w) * nz.w;
    *(float4*)(slots + base) = o;
}

// ---------------- k1: x = LN(inputs); k = x@Wk^T; v = x@Wv^T (bf16 out) ----
// 256 threads = 4 waves; each wave owns 16 rows (wave-private LDS tiles).
// MFMA 16x16x32 bf16. LDS XOR-swizzle ((row&7)<<4) on A tile and out tiles.
__global__ __launch_bounds__(256, 2) void k1_ln_kv(
    const float* __restrict__ inp, const float* __restrict__ Wk,
    const float* __restrict__ Wv, const float* __restrict__ lng,
    const float* __restrict__ lnb, uint16_t* __restrict__ kout,
    uint16_t* __restrict__ vout) {
    __shared__ uint16_t lX[4][16 * 64];     // per-wave A tile (bf16, swizzled)
    __shared__ uint16_t lO[4][2][16 * 64];  // per-wave k/v out tiles (swizzled)

    const int t = threadIdx.x;
    const int w = t >> 6;
    const int l = t & 63;

    // ---- preload B-fragments (Wk^T / Wv^T) into registers (per-lane) ----
    // B[k][n] = W[n][k]; frag: col n = (l&15)+16*nt, k = 32*s + 8*(l>>4)+i
    bf16x8 bk[4][2], bv[4][2];
    {
        const int col = l & 15;
        const int g = l >> 4;
#pragma unroll
        for (int nt = 0; nt < 4; ++nt)
#pragma unroll
            for (int s = 0; s < 2; ++s) {
                const int j = col + 16 * nt;
                const int d0 = 32 * s + 8 * g;
                const float* pk = Wk + j * 64 + d0;
                const float* pv = Wv + j * 64 + d0;
                bf16x8 fk, fv;
#pragma unroll
                for (int i = 0; i < 8; ++i) {
                    fk[i] = (short)f2bf(pk[i]);
                    fv[i] = (short)f2bf(pv[i]);
                }
                bk[nt][s] = fk;
                bv[nt][s] = fv;
            }
    }

    // per-thread LN gamma/beta for cols c0..c0+15
    const int c0 = (t & 3) * 16;
    float gv[16], bt[16];
#pragma unroll
    for (int i = 0; i < 16; ++i) { gv[i] = lng[c0 + i]; bt[i] = lnb[c0 + i]; }

    for (int c = 0; c < 8; ++c) {
        const long chunk = (long)blockIdx.x * 8 + c;
        const long rowbase = chunk * 64;
        const int rloc = t >> 2;  // chunk-local row 0..63 (wave-local: 16w..16w+15)

        // ---- load 16 floats of my row ----
        const float* src = inp + (rowbase + rloc) * 64 + c0;
        float x[16];
#pragma unroll
        for (int u = 0; u < 4; ++u) {
            float4 v4 = *(const float4*)(src + u * 4);
            x[u * 4 + 0] = v4.x; x[u * 4 + 1] = v4.y;
            x[u * 4 + 2] = v4.z; x[u * 4 + 3] = v4.w;
        }
        // ---- LN (4 lanes per row: shfl_xor 1,2) ----
        float s1 = 0.f, s2 = 0.f;
#pragma unroll
        for (int i = 0; i < 16; ++i) { s1 += x[i]; s2 += x[i] * x[i]; }
        s1 += __shfl_xor(s1, 1); s2 += __shfl_xor(s2, 1);
        s1 += __shfl_xor(s1, 2); s2 += __shfl_xor(s2, 2);
        const float mean = s1 * (1.0f / 64.0f);
        const float var = s2 * (1.0f / 64.0f) - mean * mean;
        const float rstd = rsqrtf(var + LN_EPSf);

        // ---- write normalized bf16 row into swizzled A tile ----
        const int lr = rloc & 15;
        {
            char* dst = (char*)lX[w] + lr * 128;
#pragma unroll
            for (int u = 0; u < 4; ++u) {
                u16x4 pk4;
#pragma unroll
                for (int i = 0; i < 4; ++i)
                    pk4[i] = f2bf((x[u * 4 + i] - mean) * rstd * gv[u * 4 + i] + bt[u * 4 + i]);
                const int off = (c0 * 2 + u * 8) ^ ((lr & 7) << 4);
                *(u16x4*)(dst + off) = pk4;
            }
        }
        __syncthreads();

        // ---- A-fragments + MFMA ----
        const int arow = l & 15;
        const int ag = l >> 4;
        bf16x8 a0, a1;
        {
            const char* base = (const char*)lX[w] + arow * 128;
            const int sw = (arow & 7) << 4;
            a0 = *(const bf16x8*)(base + ((16 * ag) ^ sw));
            a1 = *(const bf16x8*)(base + ((64 + 16 * ag) ^ sw));
        }
        f32x4 ack[4], acv[4];
#pragma unroll
        for (int nt = 0; nt < 4; ++nt) {
            f32x4 z = {0.f, 0.f, 0.f, 0.f};
            z = __builtin_amdgcn_mfma_f32_16x16x32_bf16(a0, bk[nt][0], z, 0, 0, 0);
            ack[nt] = __builtin_amdgcn_mfma_f32_16x16x32_bf16(a1, bk[nt][1], z, 0, 0, 0);
            f32x4 z2 = {0.f, 0.f, 0.f, 0.f};
            z2 = __builtin_amdgcn_mfma_f32_16x16x32_bf16(a0, bv[nt][0], z2, 0, 0, 0);
            acv[nt] = __builtin_amdgcn_mfma_f32_16x16x32_bf16(a1, bv[nt][1], z2, 0, 0, 0);
        }
        // ---- epilogue: C frags -> swizzled LDS out tiles (bf16) ----
        // C/D layout: col = lane&15, row = (lane>>4)*4 + reg  [HW-verified]
#pragma unroll
        for (int nt = 0; nt < 4; ++nt) {
#pragma unroll
            for (int j = 0; j < 4; ++j) {
                const int orow = ag * 4 + j;
                const int ocb = ((nt * 16 + (l & 15)) * 2) ^ ((orow & 7) << 4);
                *(uint16_t*)((char*)lO[w][0] + orow * 128 + ocb) = f2bf(ack[nt][j]);
                *(uint16_t*)((char*)lO[w][1] + orow * 128 + ocb) = f2bf(acv[nt][j]);
            }
        }
        __syncthreads();

        // ---- coalesced global store of k/v rows ----
        {
            const int sr = rloc & 15;
            const long gbase = (rowbase + w * 16 + sr) * 64 + c0;
            const int sw = (sr & 7) << 4;
#pragma unroll
            for (int m = 0; m < 2; ++m) {
                uint16_t* outp = m ? vout : kout;
                const char* lsrc = (const char*)lO[w][m] + sr * 128;
#pragma unroll
                for (int u = 0; u < 2; ++u) {
                    u16x8 val = *(const u16x8*)(lsrc + ((c0 * 2 + u * 16) ^ sw));
                    *(u16x8*)(outp + gbase + u * 8) = val;
                }
            }
        }
    }
}

// ---------------- k2: one attention pass over an N-chunk -------------------
// grid = B*PB.  threads: (pos = t>>3, dchunk = t&7).  q and accumulators in
// registers; per position: logits via 8-lane shfl reduce, softmax over K=8,
// accumulate a*v and a.  Deterministic partials to ws.
__global__ __launch_bounds__(256, 2) void k2_attn(
    const uint16_t* __restrict__ kbf, const uint16_t* __restrict__ vbf,
    const float* __restrict__ slots, const float* __restrict__ Wq,
    const float* __restrict__ lsg, const float* __restrict__ lsb,
    float* __restrict__ partials) {
    __shared__ float sraw[Kn * Dn];
    __shared__ float sln[Kn][76];
    __shared__ float qld[Kn][76];
    __shared__ float kt[64][76];
    __shared__ float vt[64][76];
    __shared__ float red[4][Kn][Dn];
    __shared__ float redas[4][Kn];

    const int t = threadIdx.x;
    const int b = blockIdx.x >> 2;
    const int part = blockIdx.x & 3;

    if (t < 128) *(float4*)(sraw + t * 4) = *(const float4*)(slots + b * 512 + t * 4);
    __syncthreads();

    // LN over slot rows (16 lanes/row)
    if (t < 128) {
        const int row = t >> 4, l16 = t & 15;
        float4 v4 = *(const float4*)(sraw + row * 64 + l16 * 4);
        float s1 = v4.x + v4.y + v4.z + v4.w;
        float s2 = v4.x * v4.x + v4.y * v4.y + v4.z * v4.z + v4.w * v4.w;
        s1 += __shfl_xor(s1, 1); s2 += __shfl_xor(s2, 1);
        s1 += __shfl_xor(s1, 2); s2 += __shfl_xor(s2, 2);
        s1 += __shfl_xor(s1, 4); s2 += __shfl_xor(s2, 4);
        s1 += __shfl_xor(s1, 8); s2 += __shfl_xor(s2, 8);
        const float mean = s1 * (1.0f / 64.0f);
        const float var = s2 * (1.0f / 64.0f) - mean * mean;
        const float rstd = rsqrtf(var + LN_EPSf);
        const float xs[4] = {v4.x, v4.y, v4.z, v4.w};
#pragma unroll
        for (int i = 0; i < 4; ++i) {
            const int dcol = l16 * 4 + i;
            sln[row][dcol] = (xs[i] - mean) * rstd * lsg[dcol] + lsb[dcol];
        }
    }
    __syncthreads();

    // q = (LN(slots) @ Wq^T) * (1/sqrt(D))
    for (int o = t; o < 512; o += 256) {
        const int kk = o >> 6, j = o & 63;
        const float* wr = Wq + j * 64;
        float acc = 0.f;
#pragma unroll
        for (int d = 0; d < 64; d += 4) {
            float4 wv = *(const float4*)(wr + d);
            float4 sv = *(const float4*)&sln[kk][d];
            acc += sv.x * wv.x + sv.y * wv.y + sv.z * wv.z + sv.w * wv.w;
        }
        qld[kk][j] = acc * SCALE_INVf;
    }
    __syncthreads();

    // load my q slice: q[kk][dc*8 + i] for all kk
    const int dc = t & 7;
    float qr[8][8];
#pragma unroll
    for (int kk = 0; kk < 8; ++kk) {
        float4 q0 = *(const float4*)&qld[kk][dc * 8];
        float4 q1 = *(const float4*)&qld[kk][dc * 8 + 4];
        qr[kk][0] = q0.x; qr[kk][1] = q0.y; qr[kk][2] = q0.z; qr[kk][3] = q0.w;
        qr[kk][4] = q1.x; qr[kk][5] = q1.y; qr[kk][6] = q1.z; qr[kk][7] = q1.w;
    }

    float upd[8][8];
    float asum[8];
#pragma unroll
    for (int kk = 0; kk < 8; ++kk) {
        asum[kk] = 0.f;
#pragma unroll
        for (int i = 0; i < 8; ++i) upd[kk][i] = 0.f;
    }

    const long kvbase = ((long)b * Nn + part * NCHUNKn) * 64;

    for (int pass = 0; pass < NCHUNKn / 64; ++pass) {
        __syncthreads();  // protect kt/vt vs previous pass reads
        // ---- stage 64 k rows + 64 v rows -> LDS f32 ----
        {
            const int row = t >> 2, h = t & 3;
            const uint16_t* ks = kbf + kvbase + (long)(pass * 64 + row) * 64 + h * 16;
            const uint16_t* vs = vbf + kvbase + (long)(pass * 64 + row) * 64 + h * 16;
            uint4 k0 = *(const uint4*)ks;
            uint4 k1 = *(const uint4*)(ks + 8);
            uint4 v0 = *(const uint4*)vs;
            uint4 v1 = *(const uint4*)(vs + 8);
            float* kd = &kt[row][h * 16];
            float* vd = &vt[row][h * 16];
            const uint32_t ku[8] = {k0.x, k0.y, k0.z, k0.w, k1.x, k1.y, k1.z, k1.w};
            const uint32_t vu[8] = {v0.x, v0.y, v0.z, v0.w, v1.x, v1.y, v1.z, v1.w};
#pragma unroll
            for (int u = 0; u < 4; ++u) {
                float4 kf, vf;
                kf.x = bflo(ku[u * 2]); kf.y = bfhi(ku[u * 2]);
                kf.z = bflo(ku[u * 2 + 1]); kf.w = bfhi(ku[u * 2 + 1]);
                vf.x = bflo(vu[u * 2]); vf.y = bfhi(vu[u * 2]);
                vf.z = bflo(vu[u * 2 + 1]); vf.w = bfhi(vu[u * 2 + 1]);
                *(float4*)(kd + u * 4) = kf;
                *(float4*)(vd + u * 4) = vf;
            }
        }
        __syncthreads();

        // ---- process 64 positions (2 per thread) ----
#pragma unroll
        for (int sub = 0; sub < 2; ++sub) {
            const int p = (t >> 3) + sub * 32;
            float4 ka = *(const float4*)&kt[p][dc * 8];
            float4 kb2 = *(const float4*)&kt[p][dc * 8 + 4];
            float4 va = *(const float4*)&vt[p][dc * 8];
            float4 vb2 = *(const float4*)&vt[p][dc * 8 + 4];
            const float kk8[8] = {ka.x, ka.y, ka.z, ka.w, kb2.x, kb2.y, kb2.z, kb2.w};
            const float vv8[8] = {va.x, va.y, va.z, va.w, vb2.x, vb2.y, vb2.z, vb2.w};
            float lg[8];
#pragma unroll
            for (int kk = 0; kk < 8; ++kk) {
                float a = 0.f;
#pragma unroll
                for (int i = 0; i < 8; ++i) a += qr[kk][i] * kk8[i];
                lg[kk] = a;
            }
            // reduce partial dots over the 8 d-chunk lanes
#pragma unroll
            for (int m = 1; m < 8; m <<= 1)
#pragma unroll
                for (int kk = 0; kk < 8; ++kk) lg[kk] += __shfl_xor(lg[kk], m);
            // softmax over the 8 slots (per position)
            float mx = lg[0];
#pragma unroll
            for (int kk = 1; kk < 8; ++kk) mx = fmaxf(mx, lg[kk]);
            float e[8];
            float es = 0.f;
#pragma unroll
            for (int kk = 0; kk < 8; ++kk) { e[kk] = __expf(lg[kk] - mx); es += e[kk]; }
            const float rinv = 1.0f / es;
#pragma unroll
            for (int kk = 0; kk < 8; ++kk) {
                const float a = e[kk] * rinv;
                asum[kk] += a;
#pragma unroll
                for (int i = 0; i < 8; ++i) upd[kk][i] += a * vv8[i];
            }
        }
    }

    // ---- reduce over position lanes within wave (bits 3..5) ----
#pragma unroll
    for (int m = 8; m < 64; m <<= 1) {
#pragma unroll
        for (int kk = 0; kk < 8; ++kk) {
#pragma unroll
            for (int i = 0; i < 8; ++i) upd[kk][i] += __shfl_xor(upd[kk][i], m);
            asum[kk] += __shfl_xor(asum[kk], m);
        }
    }
    // each lane writes kk = its p_local slice
    const int wv = t >> 6;
    const int pl = (t >> 3) & 7;
    {
        float4 u0, u1;
        u0.x = upd[0][0]; // placeholder overwritten below (avoid warnings)
        u0.x = upd[pl][0]; u0.y = upd[pl][1]; u0.z = upd[pl][2]; u0.w = upd[pl][3];
        u1.x = upd[pl][4]; u1.y = upd[pl][5]; u1.z = upd[pl][6]; u1.w = upd[pl][7];
        *(float4*)&red[wv][pl][dc * 8] = u0;
        *(float4*)&red[wv][pl][dc * 8 + 4] = u1;
        if (pl == 0) redas[wv][dc] = asum[dc];
    }
    __syncthreads();
    // ---- combine 4 waves, write partials ----
    float* pout = partials + (long)(b * PBn + part) * 520;
    if (t < 128) {
        const int idx = t * 4;
        const int kk = idx >> 6, d0 = idx & 63;
        float4 a0 = *(const float4*)&red[0][kk][d0];
        float4 a1 = *(const float4*)&red[1][kk][d0];
        float4 a2 = *(const float4*)&red[2][kk][d0];
        float4 a3 = *(const float4*)&red[3][kk][d0];
        float4 o;
        o.x = a0.x + a1.x + a2.x + a3.x;
        o.y = a0.y + a1.y + a2.y + a3.y;
        o.z = a0.z + a1.z + a2.z + a3.z;
        o.w = a0.w + a1.w + a2.w + a3.w;
        *(float4*)(pout + idx) = o;
    }
    if (t < 8) pout[512 + t] = redas[0][t] + redas[1][t] + redas[2][t] + redas[3][t];
}

// ---------------- k3: combine partials + GRU + residual MLP ---------------
__global__ __launch_bounds__(256) void k3_update(
    const float* __restrict__ partials, const float* __restrict__ slots_in,
    const float* __restrict__ wih, const float* __restrict__ whh,
    const float* __restrict__ bih, const float* __restrict__ bhh,
    const float* __restrict__ mg, const float* __restrict__ mb,
    const float* __restrict__ w1, const float* __restrict__ b1,
    const float* __restrict__ w2, const float* __restrict__ b2,
    float* __restrict__ slots_out) {
    __shared__ float updf[8][76];
    __shared__ float sp[8][76];
    __shared__ float sn[8][76];
    __shared__ float hln[8][76];
    __shared__ float gi[8][192];
    __shared__ float gh[8][192];
    __shared__ float hid[8][260];
    __shared__ float asums[8];

    const int t = threadIdx.x;
    const int b = blockIdx.x;
    const float* pp = partials + (long)b * 4 * 520;

    if (t < 8)
        asums[t] = pp[512 + t] + pp[520 + 512 + t] + pp[1040 + 512 + t] + pp[1560 + 512 + t] + EPSf;
    if (t < 128) {
        float4 v = *(const float4*)(slots_in + b * 512 + t * 4);
        const int kk = (t * 4) >> 6, d = (t * 4) & 63;
        *(float4*)&sp[kk][d] = v;
    }
    __syncthreads();
    if (t < 128) {
        const int idx = t * 4;
        const int kk = idx >> 6, d = idx & 63;
        float4 a0 = *(const float4*)(pp + idx);
        float4 a1 = *(const float4*)(pp + 520 + idx);
        float4 a2 = *(const float4*)(pp + 1040 + idx);
        float4 a3 = *(const float4*)(pp + 1560 + idx);
        const float r = 1.0f / asums[kk];
        float4 o;
        o.x = (a0.x + a1.x + a2.x + a3.x) * r;
        o.y = (a0.y + a1.y + a2.y + a3.y) * r;
        o.z = (a0.z + a1.z + a2.z + a3.z) * r;
        o.w = (a0.w + a1.w + a2.w + a3.w) * r;
        *(float4*)&updf[kk][d] = o;
    }
    __syncthreads();
    // gi = updates @ wih^T + bih ; gh = slots_prev @ whh^T + bhh
    for (int o = t; o < 1536; o += 256) {
        const int s = o / 192;
        const int j = o - s * 192;
        const float* wr1 = wih + j * 64;
        const float* wr2 = whh + j * 64;
        float a1 = bih[j], a2 = bhh[j];
#pragma unroll
        for (int d = 0; d < 64; d += 4) {
            float4 wv1 = *(const float4*)(wr1 + d);
            float4 wv2 = *(const float4*)(wr2 + d);
            float4 uv = *(const float4*)&updf[s][d];
            float4 svv = *(const float4*)&sp[s][d];
            a1 += uv.x * wv1.x + uv.y * wv1.y + uv.z * wv1.z + uv.w * wv1.w;
            a2 += svv.x * wv2.x + svv.y * wv2.y + svv.z * wv2.z + svv.w * wv2.w;
        }
        gi[s][j] = a1;
        gh[s][j] = a2;
    }
    __syncthreads();
    // gates
    for (int o = t; o < 512; o += 256) {
        const int s = o >> 6, d = o & 63;
        const float ir = gi[s][d], iz = gi[s][64 + d], in_ = gi[s][128 + d];
        const float hr = gh[s][d], hz = gh[s][64 + d], hn = gh[s][128 + d];
        const float r = 1.0f / (1.0f + __expf(-(ir + hr)));
        const float z = 1.0f / (1.0f + __expf(-(iz + hz)));
        const float n = tanhf(in_ + r * hn);
        sn[s][d] = (1.0f - z) * n + z * sp[s][d];
    }
    __syncthreads();
    // MLP layernorm
    if (t < 128) {
        const int row = t >> 4, l16 = t & 15;
        float4 v4 = *(const float4*)&sn[row][l16 * 4];
        float s1 = v4.x + v4.y + v4.z + v4.w;
        float s2 = v4.x * v4.x + v4.y * v4.y + v4.z * v4.z + v4.w * v4.w;
        s1 += __shfl_xor(s1, 1); s2 += __shfl_xor(s2, 1);
        s1 += __shfl_xor(s1, 2); s2 += __shfl_xor(s2, 2);
        s1 += __shfl_xor(s1, 4); s2 += __shfl_xor(s2, 4);
        s1 += __shfl_xor(s1, 8); s2 += __shfl_xor(s2, 8);
        const float mean = s1 * (1.0f / 64.0f);
        const float var = s2 * (1.0f / 64.0f) - mean * mean;
        const float rstd = rsqrtf(var + LN_EPSf);
        const float xs[4] = {v4.x, v4.y, v4.z, v4.w};
#pragma unroll
        for (int i = 0; i < 4; ++i) {
            const int dcol = l16 * 4 + i;
            hln[row][dcol] = (xs[i] - mean) * rstd * mg[dcol] + mb[dcol];
        }
    }
    __syncthreads();
    // hid = relu(hln @ w1^T + b1)
    for (int o = t; o < 2048; o += 256) {
        const int s = o >> 8, j = o & 255;
        const float* wr = w1 + j * 64;
        float a = b1[j];
#pragma unroll
        for (int d = 0; d < 64; d += 4) {
            float4 wv = *(const float4*)(wr + d);
            float4 hv = *(const float4*)&hln[s][d];
            a += hv.x * wv.x + hv.y * wv.y + hv.z * wv.z + hv.w * wv.w;
        }
        hid[s][j] = fmaxf(a, 0.0f);
    }
    __syncthreads();
    // out = sn + hid @ w2^T + b2
    for (int o = t; o < 512; o += 256) {
        const int s = o >> 6, d = o & 63;
        const float* wr = w2 + d * 256;
        float a = b2[d];
#pragma unroll
        for (int h = 0; h < 256; h += 4) {
            float4 wv = *(const float4*)(wr + h);
            float4 hv = *(const float4*)&hid[s][h];
            a += hv.x * wv.x + hv.y * wv.y + hv.z * wv.z + hv.w * wv.w;
        }
        slots_out[(long)b * 512 + s * 64 + d] = sn[s][d] + a;
    }
}

extern "C" void kernel_launch(void* const* d_in, const int* in_sizes, int n_in,
                              void* d_out, int out_size, void* d_ws, size_t ws_size,
                              hipStream_t stream) {
    const float* inputs = (const float*)d_in[0];
    const float* noise = (const float*)d_in[1];
    const float* mu = (const float*)d_in[2];
    const float* ls = (const float*)d_in[3];
    const float* Wq = (const float*)d_in[4];
    const float* Wk = (const float*)d_in[5];
    const float* Wv = (const float*)d_in[6];
    const float* wih = (const float*)d_in[7];
    const float* whh = (const float*)d_in[8];
    const float* bih = (const float*)d_in[9];
    const float* bhh = (const float*)d_in[10];
    const float* lng = (const float*)d_in[11];
    const float* lnb = (const float*)d_in[12];
    const float* lsg = (const float*)d_in[13];
    const float* lsb = (const float*)d_in[14];
    const float* mg = (const float*)d_in[15];
    const float* mb = (const float*)d_in[16];
    const float* w1 = (const float*)d_in[17];
    const float* b1 = (const float*)d_in[18];
    const float* w2 = (const float*)d_in[19];
    const float* b2 = (const float*)d_in[20];

    char* ws = (char*)d_ws;
    float* slots = (float*)ws;                                   // 256 KiB
    uint16_t* kbf = (uint16_t*)(ws + (1 << 18));                 // 64 MiB
    uint16_t* vbf = (uint16_t*)(ws + (1 << 18) + (1 << 26));     // 64 MiB
    float* parts = (float*)(ws + (1 << 18) + (1 << 27));         // ~1.1 MiB

    kinit<<<64, 256, 0, stream>>>(noise, mu, ls, slots);
    k1_ln_kv<<<1024, 256, 0, stream>>>(inputs, Wk, Wv, lng, lnb, kbf, vbf);
    for (int it = 0; it < 3; ++it) {
        k2_attn<<<Bn * PBn, 256, 0, stream>>>(kbf, vbf, slots, Wq, lsg, lsb, parts);
        float* dst = (it == 2) ? (float*)d_out : slots;
        k3_update<<<Bn, 256, 0, stream>>>(parts, slots, wih, whh, bih, bhh, mg, mb,
                                          w1, b1, w2, b2, dst);
    }
}

// Round 2
// 397.023 us; speedup vs baseline: 1.4678x; 1.4678x over previous
//
#include <hip/hip_runtime.h>
#include <cstdint>

#define Bn 128
#define Nn 4096
#define Dn 64
#define Kn 8
#define PBn 4
#define NCHUNKn (Nn / PBn)
#define LN_EPSf 1e-5f
#define EPSf 1e-8f
#define SCALE_INVf 0.125f

typedef short bf16x8 __attribute__((ext_vector_type(8)));
typedef float f32x4 __attribute__((ext_vector_type(4)));
typedef unsigned short u16x4 __attribute__((ext_vector_type(4)));
typedef unsigned short u16x8 __attribute__((ext_vector_type(8)));

static __device__ __forceinline__ uint16_t f2bf(float f) {
    union { float f; uint32_t u; } v; v.f = f;
    return (uint16_t)((v.u + 0x7fffu + ((v.u >> 16) & 1u)) >> 16);
}
static __device__ __forceinline__ float bflo(uint32_t u) {
    union { uint32_t u; float f; } v; v.u = u << 16; return v.f;
}
static __device__ __forceinline__ float bfhi(uint32_t u) {
    union { uint32_t u; float f; } v; v.u = u & 0xffff0000u; return v.f;
}

// ---------------- slot init: slots = mu + exp(ls)*noise ----------------
__global__ __launch_bounds__(256) void kinit(const float* __restrict__ noise,
                                             const float* __restrict__ mu,
                                             const float* __restrict__ ls,
                                             float* __restrict__ slots) {
    int i = blockIdx.x * 256 + threadIdx.x;
    int base = i * 4;
    int d = base & 63;
    float4 nz = *(const float4*)(noise + base);
    float4 m  = *(const float4*)(mu + d);
    float4 s  = *(const float4*)(ls + d);
    float4 o;
    o.x = m.x + __expf(s.x) * nz.x;
    o.y = m.y + __expf(s.y) * nz.y;
    o.z = m.z + __expf(s.z) * nz.z;
    o.w = m.w + __expf(s.w) * nz.w;
    *(float4*)(slots + base) = o;
}

// ---------------- k1: x = LN(inputs); k = x@Wk^T; v = x@Wv^T (bf16 out) ----
// 256 threads = 4 waves; each wave owns 16 rows (wave-private LDS tiles).
// MFMA 16x16x32 bf16. LDS XOR-swizzle ((row&7)<<4) on A tile and out tiles.
__global__ __launch_bounds__(256, 2) void k1_ln_kv(
    const float* __restrict__ inp, const float* __restrict__ Wk,
    const float* __restrict__ Wv, const float* __restrict__ lng,
    const float* __restrict__ lnb, uint16_t* __restrict__ kout,
    uint16_t* __restrict__ vout) {
    __shared__ uint16_t lX[4][16 * 64];     // per-wave A tile (bf16, swizzled)
    __shared__ uint16_t lO[4][2][16 * 64];  // per-wave k/v out tiles (swizzled)

    const int t = threadIdx.x;
    const int w = t >> 6;
    const int l = t & 63;

    // ---- preload B-fragments (Wk^T / Wv^T) into registers (per-lane) ----
    // B[k][n] = W[n][k]; frag: col n = (l&15)+16*nt, k = 32*s + 8*(l>>4)+i
    bf16x8 bk[4][2], bv[4][2];
    {
        const int col = l & 15;
        const int g = l >> 4;
#pragma unroll
        for (int nt = 0; nt < 4; ++nt)
#pragma unroll
            for (int s = 0; s < 2; ++s) {
                const int j = col + 16 * nt;
                const int d0 = 32 * s + 8 * g;
                const float* pk = Wk + j * 64 + d0;
                const float* pv = Wv + j * 64 + d0;
                bf16x8 fk, fv;
#pragma unroll
                for (int i = 0; i < 8; ++i) {
                    fk[i] = (short)f2bf(pk[i]);
                    fv[i] = (short)f2bf(pv[i]);
                }
                bk[nt][s] = fk;
                bv[nt][s] = fv;
            }
    }

    // per-thread LN gamma/beta for cols c0..c0+15
    const int c0 = (t & 3) * 16;
    float gv[16], bt[16];
#pragma unroll
    for (int i = 0; i < 16; ++i) { gv[i] = lng[c0 + i]; bt[i] = lnb[c0 + i]; }

    for (int c = 0; c < 8; ++c) {
        const long chunk = (long)blockIdx.x * 8 + c;
        const long rowbase = chunk * 64;
        const int rloc = t >> 2;  // chunk-local row 0..63 (wave-local: 16w..16w+15)

        // ---- load 16 floats of my row ----
        const float* src = inp + (rowbase + rloc) * 64 + c0;
        float x[16];
#pragma unroll
        for (int u = 0; u < 4; ++u) {
            float4 v4 = *(const float4*)(src + u * 4);
            x[u * 4 + 0] = v4.x; x[u * 4 + 1] = v4.y;
            x[u * 4 + 2] = v4.z; x[u * 4 + 3] = v4.w;
        }
        // ---- LN (4 lanes per row: shfl_xor 1,2) ----
        float s1 = 0.f, s2 = 0.f;
#pragma unroll
        for (int i = 0; i < 16; ++i) { s1 += x[i]; s2 += x[i] * x[i]; }
        s1 += __shfl_xor(s1, 1); s2 += __shfl_xor(s2, 1);
        s1 += __shfl_xor(s1, 2); s2 += __shfl_xor(s2, 2);
        const float mean = s1 * (1.0f / 64.0f);
        const float var = s2 * (1.0f / 64.0f) - mean * mean;
        const float rstd = rsqrtf(var + LN_EPSf);

        // ---- write normalized bf16 row into swizzled A tile ----
        const int lr = rloc & 15;
        {
            char* dst = (char*)lX[w] + lr * 128;
#pragma unroll
            for (int u = 0; u < 4; ++u) {
                u16x4 pk4;
#pragma unroll
                for (int i = 0; i < 4; ++i)
                    pk4[i] = f2bf((x[u * 4 + i] - mean) * rstd * gv[u * 4 + i] + bt[u * 4 + i]);
                const int off = (c0 * 2 + u * 8) ^ ((lr & 7) << 4);
                *(u16x4*)(dst + off) = pk4;
            }
        }
        __syncthreads();

        // ---- A-fragments + MFMA ----
        const int arow = l & 15;
        const int ag = l >> 4;
        bf16x8 a0, a1;
        {
            const char* base = (const char*)lX[w] + arow * 128;
            const int sw = (arow & 7) << 4;
            a0 = *(const bf16x8*)(base + ((16 * ag) ^ sw));
            a1 = *(const bf16x8*)(base + ((64 + 16 * ag) ^ sw));
        }
        f32x4 ack[4], acv[4];
#pragma unroll
        for (int nt = 0; nt < 4; ++nt) {
            f32x4 z = {0.f, 0.f, 0.f, 0.f};
            z = __builtin_amdgcn_mfma_f32_16x16x32_bf16(a0, bk[nt][0], z, 0, 0, 0);
            ack[nt] = __builtin_amdgcn_mfma_f32_16x16x32_bf16(a1, bk[nt][1], z, 0, 0, 0);
            f32x4 z2 = {0.f, 0.f, 0.f, 0.f};
            z2 = __builtin_amdgcn_mfma_f32_16x16x32_bf16(a0, bv[nt][0], z2, 0, 0, 0);
            acv[nt] = __builtin_amdgcn_mfma_f32_16x16x32_bf16(a1, bv[nt][1], z2, 0, 0, 0);
        }
        // ---- epilogue: C frags -> swizzled LDS out tiles (bf16) ----
        // C/D layout: col = lane&15, row = (lane>>4)*4 + reg  [HW-verified]
#pragma unroll
        for (int nt = 0; nt < 4; ++nt) {
#pragma unroll
            for (int j = 0; j < 4; ++j) {
                const int orow = ag * 4 + j;
                const int ocb = ((nt * 16 + (l & 15)) * 2) ^ ((orow & 7) << 4);
                *(uint16_t*)((char*)lO[w][0] + orow * 128 + ocb) = f2bf(ack[nt][j]);
                *(uint16_t*)((char*)lO[w][1] + orow * 128 + ocb) = f2bf(acv[nt][j]);
            }
        }
        __syncthreads();

        // ---- coalesced global store of k/v rows ----
        {
            const int sr = rloc & 15;
            const long gbase = (rowbase + w * 16 + sr) * 64 + c0;
            const int sw = (sr & 7) << 4;
#pragma unroll
            for (int m = 0; m < 2; ++m) {
                uint16_t* outp = m ? vout : kout;
                const char* lsrc = (const char*)lO[w][m] + sr * 128;
#pragma unroll
                for (int u = 0; u < 2; ++u) {
                    u16x8 val = *(const u16x8*)(lsrc + ((c0 * 2 + u * 16) ^ sw));
                    *(u16x8*)(outp + gbase + u * 8) = val;
                }
            }
        }
    }
}

// ---------------- k2: one attention pass over an N-chunk -------------------
// grid = B*PB.  threads: (pos = t>>3, dchunk = t&7).  q and accumulators in
// registers; per position: logits via 8-lane shfl reduce, softmax over K=8,
// accumulate a*v and a.  Deterministic partials to ws.
// NOTE: all register-array accesses are compile-time indexed (rule #20) —
// the epilogue writes all 8 kk slices from the pl==0 lanes, unrolled.
__global__ __launch_bounds__(256, 2) void k2_attn(
    const uint16_t* __restrict__ kbf, const uint16_t* __restrict__ vbf,
    const float* __restrict__ slots, const float* __restrict__ Wq,
    const float* __restrict__ lsg, const float* __restrict__ lsb,
    float* __restrict__ partials) {
    __shared__ float sraw[Kn * Dn];
    __shared__ float sln[Kn][76];
    __shared__ float qld[Kn][76];
    __shared__ float kt[64][76];
    __shared__ float vt[64][76];
    __shared__ float red[4][Kn][Dn];
    __shared__ float redas[4][Kn];

    const int t = threadIdx.x;
    const int b = blockIdx.x >> 2;
    const int part = blockIdx.x & 3;

    if (t < 128) *(float4*)(sraw + t * 4) = *(const float4*)(slots + b * 512 + t * 4);
    __syncthreads();

    // LN over slot rows (16 lanes/row)
    if (t < 128) {
        const int row = t >> 4, l16 = t & 15;
        float4 v4 = *(const float4*)(sraw + row * 64 + l16 * 4);
        float s1 = v4.x + v4.y + v4.z + v4.w;
        float s2 = v4.x * v4.x + v4.y * v4.y + v4.z * v4.z + v4.w * v4.w;
        s1 += __shfl_xor(s1, 1); s2 += __shfl_xor(s2, 1);
        s1 += __shfl_xor(s1, 2); s2 += __shfl_xor(s2, 2);
        s1 += __shfl_xor(s1, 4); s2 += __shfl_xor(s2, 4);
        s1 += __shfl_xor(s1, 8); s2 += __shfl_xor(s2, 8);
        const float mean = s1 * (1.0f / 64.0f);
        const float var = s2 * (1.0f / 64.0f) - mean * mean;
        const float rstd = rsqrtf(var + LN_EPSf);
        const float xs[4] = {v4.x, v4.y, v4.z, v4.w};
#pragma unroll
        for (int i = 0; i < 4; ++i) {
            const int dcol = l16 * 4 + i;
            sln[row][dcol] = (xs[i] - mean) * rstd * lsg[dcol] + lsb[dcol];
        }
    }
    __syncthreads();

    // q = (LN(slots) @ Wq^T) * (1/sqrt(D))
    for (int o = t; o < 512; o += 256) {
        const int kk = o >> 6, j = o & 63;
        const float* wr = Wq + j * 64;
        float acc = 0.f;
#pragma unroll
        for (int d = 0; d < 64; d += 4) {
            float4 wv = *(const float4*)(wr + d);
            float4 sv = *(const float4*)&sln[kk][d];
            acc += sv.x * wv.x + sv.y * wv.y + sv.z * wv.z + sv.w * wv.w;
        }
        qld[kk][j] = acc * SCALE_INVf;
    }
    __syncthreads();

    // load my q slice: q[kk][dc*8 + i] for all kk
    const int dc = t & 7;
    float qr[8][8];
#pragma unroll
    for (int kk = 0; kk < 8; ++kk) {
        float4 q0 = *(const float4*)&qld[kk][dc * 8];
        float4 q1 = *(const float4*)&qld[kk][dc * 8 + 4];
        qr[kk][0] = q0.x; qr[kk][1] = q0.y; qr[kk][2] = q0.z; qr[kk][3] = q0.w;
        qr[kk][4] = q1.x; qr[kk][5] = q1.y; qr[kk][6] = q1.z; qr[kk][7] = q1.w;
    }

    float upd[8][8];
    float asum[8];
#pragma unroll
    for (int kk = 0; kk < 8; ++kk) {
        asum[kk] = 0.f;
#pragma unroll
        for (int i = 0; i < 8; ++i) upd[kk][i] = 0.f;
    }

    const long kvbase = ((long)b * Nn + part * NCHUNKn) * 64;

    for (int pass = 0; pass < NCHUNKn / 64; ++pass) {
        __syncthreads();  // protect kt/vt vs previous pass reads
        // ---- stage 64 k rows + 64 v rows -> LDS f32 ----
        {
            const int row = t >> 2, h = t & 3;
            const uint16_t* ks = kbf + kvbase + (long)(pass * 64 + row) * 64 + h * 16;
            const uint16_t* vs = vbf + kvbase + (long)(pass * 64 + row) * 64 + h * 16;
            uint4 k0 = *(const uint4*)ks;
            uint4 k1 = *(const uint4*)(ks + 8);
            uint4 v0 = *(const uint4*)vs;
            uint4 v1 = *(const uint4*)(vs + 8);
            float* kd = &kt[row][h * 16];
            float* vd = &vt[row][h * 16];
            const uint32_t ku[8] = {k0.x, k0.y, k0.z, k0.w, k1.x, k1.y, k1.z, k1.w};
            const uint32_t vu[8] = {v0.x, v0.y, v0.z, v0.w, v1.x, v1.y, v1.z, v1.w};
#pragma unroll
            for (int u = 0; u < 4; ++u) {
                float4 kf, vf;
                kf.x = bflo(ku[u * 2]); kf.y = bfhi(ku[u * 2]);
                kf.z = bflo(ku[u * 2 + 1]); kf.w = bfhi(ku[u * 2 + 1]);
                vf.x = bflo(vu[u * 2]); vf.y = bfhi(vu[u * 2]);
                vf.z = bflo(vu[u * 2 + 1]); vf.w = bfhi(vu[u * 2 + 1]);
                *(float4*)(kd + u * 4) = kf;
                *(float4*)(vd + u * 4) = vf;
            }
        }
        __syncthreads();

        // ---- process 64 positions (2 per thread) ----
#pragma unroll
        for (int sub = 0; sub < 2; ++sub) {
            const int p = (t >> 3) + sub * 32;
            float4 ka = *(const float4*)&kt[p][dc * 8];
            float4 kb2 = *(const float4*)&kt[p][dc * 8 + 4];
            float4 va = *(const float4*)&vt[p][dc * 8];
            float4 vb2 = *(const float4*)&vt[p][dc * 8 + 4];
            const float kk8[8] = {ka.x, ka.y, ka.z, ka.w, kb2.x, kb2.y, kb2.z, kb2.w};
            const float vv8[8] = {va.x, va.y, va.z, va.w, vb2.x, vb2.y, vb2.z, vb2.w};
            float lg[8];
#pragma unroll
            for (int kk = 0; kk < 8; ++kk) {
                float a = 0.f;
#pragma unroll
                for (int i = 0; i < 8; ++i) a += qr[kk][i] * kk8[i];
                lg[kk] = a;
            }
            // reduce partial dots over the 8 d-chunk lanes
#pragma unroll
            for (int m = 1; m < 8; m <<= 1)
#pragma unroll
                for (int kk = 0; kk < 8; ++kk) lg[kk] += __shfl_xor(lg[kk], m);
            // softmax over the 8 slots (per position)
            float mx = lg[0];
#pragma unroll
            for (int kk = 1; kk < 8; ++kk) mx = fmaxf(mx, lg[kk]);
            float e[8];
            float es = 0.f;
#pragma unroll
            for (int kk = 0; kk < 8; ++kk) { e[kk] = __expf(lg[kk] - mx); es += e[kk]; }
            const float rinv = 1.0f / es;
#pragma unroll
            for (int kk = 0; kk < 8; ++kk) {
                const float a = e[kk] * rinv;
                asum[kk] += a;
#pragma unroll
                for (int i = 0; i < 8; ++i) upd[kk][i] += a * vv8[i];
            }
        }
    }

    // ---- reduce over position lanes within wave (bits 3..5) ----
#pragma unroll
    for (int m = 8; m < 64; m <<= 1) {
#pragma unroll
        for (int kk = 0; kk < 8; ++kk) {
#pragma unroll
            for (int i = 0; i < 8; ++i) upd[kk][i] += __shfl_xor(upd[kk][i], m);
            asum[kk] += __shfl_xor(asum[kk], m);
        }
    }
    // After the reduce, all 8 position-lane groups hold identical values.
    // Lanes with pl==0 (l = 0..7, i.e. dc = 0..7) write ALL kk slices with
    // compile-time indices — upd/asum stay in registers (no scratch).
    const int wv = t >> 6;
    const int l = t & 63;
    if (l < 8) {  // pl == 0, dc == l
#pragma unroll
        for (int kk = 0; kk < 8; ++kk) {
            float4 u0, u1;
            u0.x = upd[kk][0]; u0.y = upd[kk][1]; u0.z = upd[kk][2]; u0.w = upd[kk][3];
            u1.x = upd[kk][4]; u1.y = upd[kk][5]; u1.z = upd[kk][6]; u1.w = upd[kk][7];
            *(float4*)&red[wv][kk][l * 8] = u0;
            *(float4*)&red[wv][kk][l * 8 + 4] = u1;
        }
        if (l == 0) {
#pragma unroll
            for (int kk = 0; kk < 8; ++kk) redas[wv][kk] = asum[kk];
        }
    }
    __syncthreads();
    // ---- combine 4 waves, write partials ----
    float* pout = partials + (long)(b * PBn + part) * 520;
    if (t < 128) {
        const int idx = t * 4;
        const int kk = idx >> 6, d0 = idx & 63;
        float4 a0 = *(const float4*)&red[0][kk][d0];
        float4 a1 = *(const float4*)&red[1][kk][d0];
        float4 a2 = *(const float4*)&red[2][kk][d0];
        float4 a3 = *(const float4*)&red[3][kk][d0];
        float4 o;
        o.x = a0.x + a1.x + a2.x + a3.x;
        o.y = a0.y + a1.y + a2.y + a3.y;
        o.z = a0.z + a1.z + a2.z + a3.z;
        o.w = a0.w + a1.w + a2.w + a3.w;
        *(float4*)(pout + idx) = o;
    }
    if (t < 8) pout[512 + t] = redas[0][t] + redas[1][t] + redas[2][t] + redas[3][t];
}

// ---------------- k3: combine partials + GRU + residual MLP ---------------
__global__ __launch_bounds__(256) void k3_update(
    const float* __restrict__ partials, const float* __restrict__ slots_in,
    const float* __restrict__ wih, const float* __restrict__ whh,
    const float* __restrict__ bih, const float* __restrict__ bhh,
    const float* __restrict__ mg, const float* __restrict__ mb,
    const float* __restrict__ w1, const float* __restrict__ b1,
    const float* __restrict__ w2, const float* __restrict__ b2,
    float* __restrict__ slots_out) {
    __shared__ float updf[8][76];
    __shared__ float sp[8][76];
    __shared__ float sn[8][76];
    __shared__ float hln[8][76];
    __shared__ float gi[8][192];
    __shared__ float gh[8][192];
    __shared__ float hid[8][260];
    __shared__ float asums[8];

    const int t = threadIdx.x;
    const int b = blockIdx.x;
    const float* pp = partials + (long)b * 4 * 520;

    if (t < 8)
        asums[t] = pp[512 + t] + pp[520 + 512 + t] + pp[1040 + 512 + t] + pp[1560 + 512 + t] + EPSf;
    if (t < 128) {
        float4 v = *(const float4*)(slots_in + b * 512 + t * 4);
        const int kk = (t * 4) >> 6, d = (t * 4) & 63;
        *(float4*)&sp[kk][d] = v;
    }
    __syncthreads();
    if (t < 128) {
        const int idx = t * 4;
        const int kk = idx >> 6, d = idx & 63;
        float4 a0 = *(const float4*)(pp + idx);
        float4 a1 = *(const float4*)(pp + 520 + idx);
        float4 a2 = *(const float4*)(pp + 1040 + idx);
        float4 a3 = *(const float4*)(pp + 1560 + idx);
        const float r = 1.0f / asums[kk];
        float4 o;
        o.x = (a0.x + a1.x + a2.x + a3.x) * r;
        o.y = (a0.y + a1.y + a2.y + a3.y) * r;
        o.z = (a0.z + a1.z + a2.z + a3.z) * r;
        o.w = (a0.w + a1.w + a2.w + a3.w) * r;
        *(float4*)&updf[kk][d] = o;
    }
    __syncthreads();
    // gi = updates @ wih^T + bih ; gh = slots_prev @ whh^T + bhh
    for (int o = t; o < 1536; o += 256) {
        const int s = o / 192;
        const int j = o - s * 192;
        const float* wr1 = wih + j * 64;
        const float* wr2 = whh + j * 64;
        float a1 = bih[j], a2 = bhh[j];
#pragma unroll
        for (int d = 0; d < 64; d += 4) {
            float4 wv1 = *(const float4*)(wr1 + d);
            float4 wv2 = *(const float4*)(wr2 + d);
            float4 uv = *(const float4*)&updf[s][d];
            float4 svv = *(const float4*)&sp[s][d];
            a1 += uv.x * wv1.x + uv.y * wv1.y + uv.z * wv1.z + uv.w * wv1.w;
            a2 += svv.x * wv2.x + svv.y * wv2.y + svv.z * wv2.z + svv.w * wv2.w;
        }
        gi[s][j] = a1;
        gh[s][j] = a2;
    }
    __syncthreads();
    // gates
    for (int o = t; o < 512; o += 256) {
        const int s = o >> 6, d = o & 63;
        const float ir = gi[s][d], iz = gi[s][64 + d], in_ = gi[s][128 + d];
        const float hr = gh[s][d], hz = gh[s][64 + d], hn = gh[s][128 + d];
        const float r = 1.0f / (1.0f + __expf(-(ir + hr)));
        const float z = 1.0f / (1.0f + __expf(-(iz + hz)));
        const float n = tanhf(in_ + r * hn);
        sn[s][d] = (1.0f - z) * n + z * sp[s][d];
    }
    __syncthreads();
    // MLP layernorm
    if (t < 128) {
        const int row = t >> 4, l16 = t & 15;
        float4 v4 = *(const float4*)&sn[row][l16 * 4];
        float s1 = v4.x + v4.y + v4.z + v4.w;
        float s2 = v4.x * v4.x + v4.y * v4.y + v4.z * v4.z + v4.w * v4.w;
        s1 += __shfl_xor(s1, 1); s2 += __shfl_xor(s2, 1);
        s1 += __shfl_xor(s1, 2); s2 += __shfl_xor(s2, 2);
        s1 += __shfl_xor(s1, 4); s2 += __shfl_xor(s2, 4);
        s1 += __shfl_xor(s1, 8); s2 += __shfl_xor(s2, 8);
        const float mean = s1 * (1.0f / 64.0f);
        const float var = s2 * (1.0f / 64.0f) - mean * mean;
        const float rstd = rsqrtf(var + LN_EPSf);
        const float xs[4] = {v4.x, v4.y, v4.z, v4.w};
#pragma unroll
        for (int i = 0; i < 4; ++i) {
            const int dcol = l16 * 4 + i;
            hln[row][dcol] = (xs[i] - mean) * rstd * mg[dcol] + mb[dcol];
        }
    }
    __syncthreads();
    // hid = relu(hln @ w1^T + b1)
    for (int o = t; o < 2048; o += 256) {
        const int s = o >> 8, j = o & 255;
        const float* wr = w1 + j * 64;
        float a = b1[j];
#pragma unroll
        for (int d = 0; d < 64; d += 4) {
            float4 wv = *(const float4*)(wr + d);
            float4 hv = *(const float4*)&hln[s][d];
            a += hv.x * wv.x + hv.y * wv.y + hv.z * wv.z + hv.w * wv.w;
        }
        hid[s][j] = fmaxf(a, 0.0f);
    }
    __syncthreads();
    // out = sn + hid @ w2^T + b2
    for (int o = t; o < 512; o += 256) {
        const int s = o >> 6, d = o & 63;
        const float* wr = w2 + d * 256;
        float a = b2[d];
#pragma unroll
        for (int h = 0; h < 256; h += 4) {
            float4 wv = *(const float4*)(wr + h);
            float4 hv = *(const float4*)&hid[s][h];
            a += hv.x * wv.x + hv.y * wv.y + hv.z * wv.z + hv.w * wv.w;
        }
        slots_out[(long)b * 512 + s * 64 + d] = sn[s][d] + a;
    }
}

extern "C" void kernel_launch(void* const* d_in, const int* in_sizes, int n_in,
                              void* d_out, int out_size, void* d_ws, size_t ws_size,
                              hipStream_t stream) {
    const float* inputs = (const float*)d_in[0];
    const float* noise = (const float*)d_in[1];
    const float* mu = (const float*)d_in[2];
    const float* ls = (const float*)d_in[3];
    const float* Wq = (const float*)d_in[4];
    const float* Wk = (const float*)d_in[5];
    const float* Wv = (const float*)d_in[6];
    const float* wih = (const float*)d_in[7];
    const float* whh = (const float*)d_in[8];
    const float* bih = (const float*)d_in[9];
    const float* bhh = (const float*)d_in[10];
    const float* lng = (const float*)d_in[11];
    const float* lnb = (const float*)d_in[12];
    const float* lsg = (const float*)d_in[13];
    const float* lsb = (const float*)d_in[14];
    const float* mg = (const float*)d_in[15];
    const float* mb = (const float*)d_in[16];
    const float* w1 = (const float*)d_in[17];
    const float* b1 = (const float*)d_in[18];
    const float* w2 = (const float*)d_in[19];
    const float* b2 = (const float*)d_in[20];

    char* ws = (char*)d_ws;
    float* slots = (float*)ws;                                   // 256 KiB
    uint16_t* kbf = (uint16_t*)(ws + (1 << 18));                 // 64 MiB
    uint16_t* vbf = (uint16_t*)(ws + (1 << 18) + (1 << 26));     // 64 MiB
    float* parts = (float*)(ws + (1 << 18) + (1 << 27));         // ~1.1 MiB

    kinit<<<64, 256, 0, stream>>>(noise, mu, ls, slots);
    k1_ln_kv<<<1024, 256, 0, stream>>>(inputs, Wk, Wv, lng, lnb, kbf, vbf);
    for (int it = 0; it < 3; ++it) {
        k2_attn<<<Bn * PBn, 256, 0, stream>>>(kbf, vbf, slots, Wq, lsg, lsb, parts);
        float* dst = (it == 2) ? (float*)d_out : slots;
        k3_update<<<Bn, 256, 0, stream>>>(parts, slots, wih, whh, bih, bhh, mg, mb,
                                          w1, b1, w2, b2, dst);
    }
}

// Round 3
// 360.411 us; speedup vs baseline: 1.6170x; 1.1016x over previous
//
#include <hip/hip_runtime.h>
#include <cstdint>

#define Bn 128
#define Nn 4096
#define Dn 64
#define Kn 8
#define PBn 8
#define NCHUNKn (Nn / PBn)
#define LN_EPSf 1e-5f
#define EPSf 1e-8f
#define SCALE_INVf 0.125f

typedef short bf16x8 __attribute__((ext_vector_type(8)));
typedef float f32x4 __attribute__((ext_vector_type(4)));
typedef unsigned short u16x4 __attribute__((ext_vector_type(4)));
typedef unsigned short u16x8 __attribute__((ext_vector_type(8)));

static __device__ __forceinline__ uint16_t f2bf(float f) {
    union { float f; uint32_t u; } v; v.f = f;
    return (uint16_t)((v.u + 0x7fffu + ((v.u >> 16) & 1u)) >> 16);
}
static __device__ __forceinline__ float bflo(uint32_t u) {
    union { uint32_t u; float f; } v; v.u = u << 16; return v.f;
}
static __device__ __forceinline__ float bfhi(uint32_t u) {
    union { uint32_t u; float f; } v; v.u = u & 0xffff0000u; return v.f;
}

// ---------------- slot init: slots = mu + exp(ls)*noise ----------------
__global__ __launch_bounds__(256) void kinit(const float* __restrict__ noise,
                                             const float* __restrict__ mu,
                                             const float* __restrict__ ls,
                                             float* __restrict__ slots) {
    int i = blockIdx.x * 256 + threadIdx.x;
    int base = i * 4;
    int d = base & 63;
    float4 nz = *(const float4*)(noise + base);
    float4 m  = *(const float4*)(mu + d);
    float4 s  = *(const float4*)(ls + d);
    float4 o;
    o.x = m.x + __expf(s.x) * nz.x;
    o.y = m.y + __expf(s.y) * nz.y;
    o.z = m.z + __expf(s.z) * nz.z;
    o.w = m.w + __expf(s.w) * nz.w;
    *(float4*)(slots + base) = o;
}

// ---------------- k1: x = LN(inputs); k = x@Wk^T; v = x@Wv^T (bf16 out) ----
// 256 threads = 4 waves; each wave owns 16 rows.  ALL LDS tiles are
// wave-private -> NO __syncthreads(); wave_barrier() (zero-cost compiler
// fence) only.  Next-chunk input prefetched into registers so HBM latency
// hides under LN/MFMA of the current chunk.
__global__ __launch_bounds__(256, 2) void k1_ln_kv(
    const float* __restrict__ inp, const float* __restrict__ Wk,
    const float* __restrict__ Wv, const float* __restrict__ lng,
    const float* __restrict__ lnb, uint16_t* __restrict__ kout,
    uint16_t* __restrict__ vout) {
    __shared__ uint16_t lX[4][16 * 64];     // per-wave A tile (bf16, swizzled)
    __shared__ uint16_t lO[4][2][16 * 64];  // per-wave k/v out tiles (swizzled)

    const int t = threadIdx.x;
    const int w = t >> 6;
    const int l = t & 63;

    // ---- preload B-fragments (Wk^T / Wv^T) into registers (per-lane) ----
    bf16x8 bk[4][2], bv[4][2];
    {
        const int col = l & 15;
        const int g = l >> 4;
#pragma unroll
        for (int nt = 0; nt < 4; ++nt)
#pragma unroll
            for (int s = 0; s < 2; ++s) {
                const int j = col + 16 * nt;
                const int d0 = 32 * s + 8 * g;
                const float* pk = Wk + j * 64 + d0;
                const float* pv = Wv + j * 64 + d0;
                bf16x8 fk, fv;
#pragma unroll
                for (int i = 0; i < 8; ++i) {
                    fk[i] = (short)f2bf(pk[i]);
                    fv[i] = (short)f2bf(pv[i]);
                }
                bk[nt][s] = fk;
                bv[nt][s] = fv;
            }
    }

    const int c0 = (t & 3) * 16;
    float gv[16], bt[16];
#pragma unroll
    for (int i = 0; i < 16; ++i) { gv[i] = lng[c0 + i]; bt[i] = lnb[c0 + i]; }

    const int rloc = t >> 2;  // chunk-local row 0..63
    const long blockbase = (long)blockIdx.x * 8 * 64;

    // prefetch chunk 0
    float x[16];
    {
        const float* src = inp + (blockbase + rloc) * 64 + c0;
#pragma unroll
        for (int u = 0; u < 4; ++u) {
            float4 v4 = *(const float4*)(src + u * 4);
            x[u * 4 + 0] = v4.x; x[u * 4 + 1] = v4.y;
            x[u * 4 + 2] = v4.z; x[u * 4 + 3] = v4.w;
        }
    }

    for (int c = 0; c < 8; ++c) {
        const long rowbase = blockbase + (long)c * 64;

        // ---- prefetch next chunk ----
        float xn[16];
        if (c < 7) {
            const float* src = inp + (rowbase + 64 + rloc) * 64 + c0;
#pragma unroll
            for (int u = 0; u < 4; ++u) {
                float4 v4 = *(const float4*)(src + u * 4);
                xn[u * 4 + 0] = v4.x; xn[u * 4 + 1] = v4.y;
                xn[u * 4 + 2] = v4.z; xn[u * 4 + 3] = v4.w;
            }
        }

        // ---- LN (4 lanes per row) ----
        float s1 = 0.f, s2 = 0.f;
#pragma unroll
        for (int i = 0; i < 16; ++i) { s1 += x[i]; s2 += x[i] * x[i]; }
        s1 += __shfl_xor(s1, 1); s2 += __shfl_xor(s2, 1);
        s1 += __shfl_xor(s1, 2); s2 += __shfl_xor(s2, 2);
        const float mean = s1 * (1.0f / 64.0f);
        const float var = s2 * (1.0f / 64.0f) - mean * mean;
        const float rstd = rsqrtf(var + LN_EPSf);

        // ---- write normalized bf16 row into swizzled A tile (wave-private) ----
        const int lr = rloc & 15;
        {
            char* dst = (char*)lX[w] + lr * 128;
#pragma unroll
            for (int u = 0; u < 4; ++u) {
                u16x4 pk4;
#pragma unroll
                for (int i = 0; i < 4; ++i)
                    pk4[i] = f2bf((x[u * 4 + i] - mean) * rstd * gv[u * 4 + i] + bt[u * 4 + i]);
                const int off = (c0 * 2 + u * 8) ^ ((lr & 7) << 4);
                *(u16x4*)(dst + off) = pk4;
            }
        }
        __builtin_amdgcn_wave_barrier();

        // ---- A-fragments + MFMA ----
        const int arow = l & 15;
        const int ag = l >> 4;
        bf16x8 a0, a1;
        {
            const char* base = (const char*)lX[w] + arow * 128;
            const int sw = (arow & 7) << 4;
            a0 = *(const bf16x8*)(base + ((16 * ag) ^ sw));
            a1 = *(const bf16x8*)(base + ((64 + 16 * ag) ^ sw));
        }
        f32x4 ack[4], acv[4];
#pragma unroll
        for (int nt = 0; nt < 4; ++nt) {
            f32x4 z = {0.f, 0.f, 0.f, 0.f};
            z = __builtin_amdgcn_mfma_f32_16x16x32_bf16(a0, bk[nt][0], z, 0, 0, 0);
            ack[nt] = __builtin_amdgcn_mfma_f32_16x16x32_bf16(a1, bk[nt][1], z, 0, 0, 0);
            f32x4 z2 = {0.f, 0.f, 0.f, 0.f};
            z2 = __builtin_amdgcn_mfma_f32_16x16x32_bf16(a0, bv[nt][0], z2, 0, 0, 0);
            acv[nt] = __builtin_amdgcn_mfma_f32_16x16x32_bf16(a1, bv[nt][1], z2, 0, 0, 0);
        }
        // ---- epilogue: C frags -> swizzled LDS out tiles (wave-private) ----
        // C/D layout: col = lane&15, row = (lane>>4)*4 + reg  [HW-verified]
#pragma unroll
        for (int nt = 0; nt < 4; ++nt) {
#pragma unroll
            for (int j = 0; j < 4; ++j) {
                const int orow = ag * 4 + j;
                const int ocb = ((nt * 16 + (l & 15)) * 2) ^ ((orow & 7) << 4);
                *(uint16_t*)((char*)lO[w][0] + orow * 128 + ocb) = f2bf(ack[nt][j]);
                *(uint16_t*)((char*)lO[w][1] + orow * 128 + ocb) = f2bf(acv[nt][j]);
            }
        }
        __builtin_amdgcn_wave_barrier();

        // ---- coalesced global store of k/v rows ----
        {
            const int sr = rloc & 15;
            const long gbase = (rowbase + w * 16 + sr) * 64 + c0;
            const int sw = (sr & 7) << 4;
#pragma unroll
            for (int m = 0; m < 2; ++m) {
                uint16_t* outp = m ? vout : kout;
                const char* lsrc = (const char*)lO[w][m] + sr * 128;
#pragma unroll
                for (int u = 0; u < 2; ++u) {
                    u16x8 val = *(const u16x8*)(lsrc + ((c0 * 2 + u * 16) ^ sw));
                    *(u16x8*)(outp + gbase + u * 8) = val;
                }
            }
        }
        __builtin_amdgcn_wave_barrier();

#pragma unroll
        for (int i = 0; i < 16; ++i) x[i] = xn[i];
    }
}

// ---------------- k2: one attention pass over an N-chunk -------------------
// grid = B*PBn.  threads: (pg = t>>3, dc = t&7).  NO k/v LDS staging: each
// thread reads its 16B k/v slices straight from global (8 lanes x 16B = fully
// coalesced 128B per row).  q + accumulators in registers; logits reduced
// over the 8 dc lanes via shfl_xor; softmax over K=8 per position.
// All register arrays are compile-time indexed.
__global__ __launch_bounds__(256) void k2_attn(
    const uint16_t* __restrict__ kbf, const uint16_t* __restrict__ vbf,
    const float* __restrict__ slots, const float* __restrict__ Wq,
    const float* __restrict__ lsg, const float* __restrict__ lsb,
    float* __restrict__ partials) {
    __shared__ float sraw[Kn * Dn];
    __shared__ float sln[Kn][76];
    __shared__ float qld[Kn][76];
    __shared__ float red[4][Kn][Dn];
    __shared__ float redas[4][Kn];

    const int t = threadIdx.x;
    const int b = blockIdx.x >> 3;
    const int part = blockIdx.x & 7;

    if (t < 128) *(float4*)(sraw + t * 4) = *(const float4*)(slots + b * 512 + t * 4);
    __syncthreads();

    // LN over slot rows (16 lanes/row)
    if (t < 128) {
        const int row = t >> 4, l16 = t & 15;
        float4 v4 = *(const float4*)(sraw + row * 64 + l16 * 4);
        float s1 = v4.x + v4.y + v4.z + v4.w;
        float s2 = v4.x * v4.x + v4.y * v4.y + v4.z * v4.z + v4.w * v4.w;
        s1 += __shfl_xor(s1, 1); s2 += __shfl_xor(s2, 1);
        s1 += __shfl_xor(s1, 2); s2 += __shfl_xor(s2, 2);
        s1 += __shfl_xor(s1, 4); s2 += __shfl_xor(s2, 4);
        s1 += __shfl_xor(s1, 8); s2 += __shfl_xor(s2, 8);
        const float mean = s1 * (1.0f / 64.0f);
        const float var = s2 * (1.0f / 64.0f) - mean * mean;
        const float rstd = rsqrtf(var + LN_EPSf);
        const float xs[4] = {v4.x, v4.y, v4.z, v4.w};
#pragma unroll
        for (int i = 0; i < 4; ++i) {
            const int dcol = l16 * 4 + i;
            sln[row][dcol] = (xs[i] - mean) * rstd * lsg[dcol] + lsb[dcol];
        }
    }
    __syncthreads();

    // q = (LN(slots) @ Wq^T) * (1/sqrt(D))
    for (int o = t; o < 512; o += 256) {
        const int kk = o >> 6, j = o & 63;
        const float* wr = Wq + j * 64;
        float acc = 0.f;
#pragma unroll
        for (int d = 0; d < 64; d += 4) {
            float4 wv = *(const float4*)(wr + d);
            float4 sv = *(const float4*)&sln[kk][d];
            acc += sv.x * wv.x + sv.y * wv.y + sv.z * wv.z + sv.w * wv.w;
        }
        qld[kk][j] = acc * SCALE_INVf;
    }
    __syncthreads();

    const int dc = t & 7;
    const int pg = t >> 3;  // 0..31
    float qr[8][8];
#pragma unroll
    for (int kk = 0; kk < 8; ++kk) {
        float4 q0 = *(const float4*)&qld[kk][dc * 8];
        float4 q1 = *(const float4*)&qld[kk][dc * 8 + 4];
        qr[kk][0] = q0.x; qr[kk][1] = q0.y; qr[kk][2] = q0.z; qr[kk][3] = q0.w;
        qr[kk][4] = q1.x; qr[kk][5] = q1.y; qr[kk][6] = q1.z; qr[kk][7] = q1.w;
    }

    float upd[8][8];
    float asum[8];
#pragma unroll
    for (int kk = 0; kk < 8; ++kk) {
        asum[kk] = 0.f;
#pragma unroll
        for (int i = 0; i < 8; ++i) upd[kk][i] = 0.f;
    }

    const long kvoff = ((long)b * Nn + part * NCHUNKn) * 64 + dc * 8;
    const uint16_t* kbase = kbf + kvoff;
    const uint16_t* vbase = vbf + kvoff;

    uint4 kr = *(const uint4*)(kbase + (long)pg * 64);
    uint4 vr = *(const uint4*)(vbase + (long)pg * 64);

    for (int it = 0; it < NCHUNKn / 32; ++it) {
        uint4 krn = kr, vrn = vr;
        if (it < NCHUNKn / 32 - 1) {
            const long o = (long)((it + 1) * 32 + pg) * 64;
            krn = *(const uint4*)(kbase + o);
            vrn = *(const uint4*)(vbase + o);
        }
        float kf[8], vf[8];
        kf[0] = bflo(kr.x); kf[1] = bfhi(kr.x);
        kf[2] = bflo(kr.y); kf[3] = bfhi(kr.y);
        kf[4] = bflo(kr.z); kf[5] = bfhi(kr.z);
        kf[6] = bflo(kr.w); kf[7] = bfhi(kr.w);
        vf[0] = bflo(vr.x); vf[1] = bfhi(vr.x);
        vf[2] = bflo(vr.y); vf[3] = bfhi(vr.y);
        vf[4] = bflo(vr.z); vf[5] = bfhi(vr.z);
        vf[6] = bflo(vr.w); vf[7] = bfhi(vr.w);

        float lg[8];
#pragma unroll
        for (int kk = 0; kk < 8; ++kk) {
            float a = 0.f;
#pragma unroll
            for (int i = 0; i < 8; ++i) a += qr[kk][i] * kf[i];
            lg[kk] = a;
        }
        // reduce partial dots over the 8 dc lanes
#pragma unroll
        for (int m = 1; m < 8; m <<= 1)
#pragma unroll
            for (int kk = 0; kk < 8; ++kk) lg[kk] += __shfl_xor(lg[kk], m);
        // softmax over the 8 slots (per position)
        float mx = lg[0];
#pragma unroll
        for (int kk = 1; kk < 8; ++kk) mx = fmaxf(mx, lg[kk]);
        float e[8];
        float es = 0.f;
#pragma unroll
        for (int kk = 0; kk < 8; ++kk) { e[kk] = __expf(lg[kk] - mx); es += e[kk]; }
        const float rinv = 1.0f / es;
#pragma unroll
        for (int kk = 0; kk < 8; ++kk) {
            const float a = e[kk] * rinv;
            asum[kk] += a;
#pragma unroll
            for (int i = 0; i < 8; ++i) upd[kk][i] += a * vf[i];
        }
        kr = krn; vr = vrn;
    }

    // ---- reduce over position-group lanes within wave (bits 3..5) ----
#pragma unroll
    for (int m = 8; m < 64; m <<= 1) {
#pragma unroll
        for (int kk = 0; kk < 8; ++kk) {
#pragma unroll
            for (int i = 0; i < 8; ++i) upd[kk][i] += __shfl_xor(upd[kk][i], m);
            asum[kk] += __shfl_xor(asum[kk], m);
        }
    }
    // lanes l<8 (pg-group 0) hold the wave total; write all kk slices with
    // compile-time indices (no scratch).
    const int wv = t >> 6;
    const int l = t & 63;
    if (l < 8) {  // dc == l
#pragma unroll
        for (int kk = 0; kk < 8; ++kk) {
            float4 u0, u1;
            u0.x = upd[kk][0]; u0.y = upd[kk][1]; u0.z = upd[kk][2]; u0.w = upd[kk][3];
            u1.x = upd[kk][4]; u1.y = upd[kk][5]; u1.z = upd[kk][6]; u1.w = upd[kk][7];
            *(float4*)&red[wv][kk][l * 8] = u0;
            *(float4*)&red[wv][kk][l * 8 + 4] = u1;
        }
        if (l == 0) {
#pragma unroll
            for (int kk = 0; kk < 8; ++kk) redas[wv][kk] = asum[kk];
        }
    }
    __syncthreads();
    // ---- combine 4 waves, write partials ----
    float* pout = partials + (long)(b * PBn + part) * 520;
    if (t < 128) {
        const int idx = t * 4;
        const int kk = idx >> 6, d0 = idx & 63;
        float4 a0 = *(const float4*)&red[0][kk][d0];
        float4 a1 = *(const float4*)&red[1][kk][d0];
        float4 a2 = *(const float4*)&red[2][kk][d0];
        float4 a3 = *(const float4*)&red[3][kk][d0];
        float4 o;
        o.x = a0.x + a1.x + a2.x + a3.x;
        o.y = a0.y + a1.y + a2.y + a3.y;
        o.z = a0.z + a1.z + a2.z + a3.z;
        o.w = a0.w + a1.w + a2.w + a3.w;
        *(float4*)(pout + idx) = o;
    }
    if (t < 8) pout[512 + t] = redas[0][t] + redas[1][t] + redas[2][t] + redas[3][t];
}

// ---------------- k3: combine partials + GRU + residual MLP ---------------
__global__ __launch_bounds__(256) void k3_update(
    const float* __restrict__ partials, const float* __restrict__ slots_in,
    const float* __restrict__ wih, const float* __restrict__ whh,
    const float* __restrict__ bih, const float* __restrict__ bhh,
    const float* __restrict__ mg, const float* __restrict__ mb,
    const float* __restrict__ w1, const float* __restrict__ b1,
    const float* __restrict__ w2, const float* __restrict__ b2,
    float* __restrict__ slots_out) {
    __shared__ float updf[8][76];
    __shared__ float sp[8][76];
    __shared__ float sn[8][76];
    __shared__ float hln[8][76];
    __shared__ float gi[8][192];
    __shared__ float gh[8][192];
    __shared__ float hid[8][260];
    __shared__ float asums[8];

    const int t = threadIdx.x;
    const int b = blockIdx.x;
    const float* pp = partials + (long)b * PBn * 520;

    if (t < 8) {
        float a = EPSf;
#pragma unroll
        for (int j = 0; j < PBn; ++j) a += pp[j * 520 + 512 + t];
        asums[t] = a;
    }
    if (t < 128) {
        float4 v = *(const float4*)(slots_in + b * 512 + t * 4);
        const int kk = (t * 4) >> 6, d = (t * 4) & 63;
        *(float4*)&sp[kk][d] = v;
    }
    __syncthreads();
    if (t < 128) {
        const int idx = t * 4;
        const int kk = idx >> 6, d = idx & 63;
        float4 o = {0.f, 0.f, 0.f, 0.f};
#pragma unroll
        for (int j = 0; j < PBn; ++j) {
            float4 a = *(const float4*)(pp + j * 520 + idx);
            o.x += a.x; o.y += a.y; o.z += a.z; o.w += a.w;
        }
        const float r = 1.0f / asums[kk];
        o.x *= r; o.y *= r; o.z *= r; o.w *= r;
        *(float4*)&updf[kk][d] = o;
    }
    __syncthreads();
    // gi = updates @ wih^T + bih ; gh = slots_prev @ whh^T + bhh
    for (int o = t; o < 1536; o += 256) {
        const int s = o / 192;
        const int j = o - s * 192;
        const float* wr1 = wih + j * 64;
        const float* wr2 = whh + j * 64;
        float a1 = bih[j], a2 = bhh[j];
#pragma unroll
        for (int d = 0; d < 64; d += 4) {
            float4 wv1 = *(const float4*)(wr1 + d);
            float4 wv2 = *(const float4*)(wr2 + d);
            float4 uv = *(const float4*)&updf[s][d];
            float4 svv = *(const float4*)&sp[s][d];
            a1 += uv.x * wv1.x + uv.y * wv1.y + uv.z * wv1.z + uv.w * wv1.w;
            a2 += svv.x * wv2.x + svv.y * wv2.y + svv.z * wv2.z + svv.w * wv2.w;
        }
        gi[s][j] = a1;
        gh[s][j] = a2;
    }
    __syncthreads();
    // gates
    for (int o = t; o < 512; o += 256) {
        const int s = o >> 6, d = o & 63;
        const float ir = gi[s][d], iz = gi[s][64 + d], in_ = gi[s][128 + d];
        const float hr = gh[s][d], hz = gh[s][64 + d], hn = gh[s][128 + d];
        const float r = 1.0f / (1.0f + __expf(-(ir + hr)));
        const float z = 1.0f / (1.0f + __expf(-(iz + hz)));
        const float n = tanhf(in_ + r * hn);
        sn[s][d] = (1.0f - z) * n + z * sp[s][d];
    }
    __syncthreads();
    // MLP layernorm
    if (t < 128) {
        const int row = t >> 4, l16 = t & 15;
        float4 v4 = *(const float4*)&sn[row][l16 * 4];
        float s1 = v4.x + v4.y + v4.z + v4.w;
        float s2 = v4.x * v4.x + v4.y * v4.y + v4.z * v4.z + v4.w * v4.w;
        s1 += __shfl_xor(s1, 1); s2 += __shfl_xor(s2, 1);
        s1 += __shfl_xor(s1, 2); s2 += __shfl_xor(s2, 2);
        s1 += __shfl_xor(s1, 4); s2 += __shfl_xor(s2, 4);
        s1 += __shfl_xor(s1, 8); s2 += __shfl_xor(s2, 8);
        const float mean = s1 * (1.0f / 64.0f);
        const float var = s2 * (1.0f / 64.0f) - mean * mean;
        const float rstd = rsqrtf(var + LN_EPSf);
        const float xs[4] = {v4.x, v4.y, v4.z, v4.w};
#pragma unroll
        for (int i = 0; i < 4; ++i) {
            const int dcol = l16 * 4 + i;
            hln[row][dcol] = (xs[i] - mean) * rstd * mg[dcol] + mb[dcol];
        }
    }
    __syncthreads();
    // hid = relu(hln @ w1^T + b1)
    for (int o = t; o < 2048; o += 256) {
        const int s = o >> 8, j = o & 255;
        const float* wr = w1 + j * 64;
        float a = b1[j];
#pragma unroll
        for (int d = 0; d < 64; d += 4) {
            float4 wv = *(const float4*)(wr + d);
            float4 hv = *(const float4*)&hln[s][d];
            a += hv.x * wv.x + hv.y * wv.y + hv.z * wv.z + hv.w * wv.w;
        }
        hid[s][j] = fmaxf(a, 0.0f);
    }
    __syncthreads();
    // out = sn + hid @ w2^T + b2
    for (int o = t; o < 512; o += 256) {
        const int s = o >> 6, d = o & 63;
        const float* wr = w2 + d * 256;
        float a = b2[d];
#pragma unroll
        for (int h = 0; h < 256; h += 4) {
            float4 wv = *(const float4*)(wr + h);
            float4 hv = *(const float4*)&hid[s][h];
            a += hv.x * wv.x + hv.y * wv.y + hv.z * wv.z + hv.w * wv.w;
        }
        slots_out[(long)b * 512 + s * 64 + d] = sn[s][d] + a;
    }
}

extern "C" void kernel_launch(void* const* d_in, const int* in_sizes, int n_in,
                              void* d_out, int out_size, void* d_ws, size_t ws_size,
                              hipStream_t stream) {
    const float* inputs = (const float*)d_in[0];
    const float* noise = (const float*)d_in[1];
    const float* mu = (const float*)d_in[2];
    const float* ls = (const float*)d_in[3];
    const float* Wq = (const float*)d_in[4];
    const float* Wk = (const float*)d_in[5];
    const float* Wv = (const float*)d_in[6];
    const float* wih = (const float*)d_in[7];
    const float* whh = (const float*)d_in[8];
    const float* bih = (const float*)d_in[9];
    const float* bhh = (const float*)d_in[10];
    const float* lng = (const float*)d_in[11];
    const float* lnb = (const float*)d_in[12];
    const float* lsg = (const float*)d_in[13];
    const float* lsb = (const float*)d_in[14];
    const float* mg = (const float*)d_in[15];
    const float* mb = (const float*)d_in[16];
    const float* w1 = (const float*)d_in[17];
    const float* b1 = (const float*)d_in[18];
    const float* w2 = (const float*)d_in[19];
    const float* b2 = (const float*)d_in[20];

    char* ws = (char*)d_ws;
    float* slots = (float*)ws;                                   // 256 KiB
    uint16_t* kbf = (uint16_t*)(ws + (1 << 18));                 // 64 MiB
    uint16_t* vbf = (uint16_t*)(ws + (1 << 18) + (1 << 26));     // 64 MiB
    float* parts = (float*)(ws + (1 << 18) + (1 << 27));         // ~2.1 MiB

    kinit<<<64, 256, 0, stream>>>(noise, mu, ls, slots);
    k1_ln_kv<<<1024, 256, 0, stream>>>(inputs, Wk, Wv, lng, lnb, kbf, vbf);
    for (int it = 0; it < 3; ++it) {
        k2_attn<<<Bn * PBn, 256, 0, stream>>>(kbf, vbf, slots, Wq, lsg, lsb, parts);
        float* dst = (it == 2) ? (float*)d_out : slots;
        k3_update<<<Bn, 256, 0, stream>>>(parts, slots, wih, whh, bih, bhh, mg, mb,
                                          w1, b1, w2, b2, dst);
    }
}

// Round 4
// 274.522 us; speedup vs baseline: 2.1228x; 1.3129x over previous
//
#include <hip/hip_runtime.h>
#include <cstdint>

#define Bn 128
#define Nn 4096
#define Dn 64
#define Kn 8
#define PBn 8
#define NCHUNKn (Nn / PBn)
#define LN_EPSf 1e-5f
#define EPSf 1e-8f

typedef unsigned short u16x8 __attribute__((ext_vector_type(8)));

static __device__ __forceinline__ uint16_t f2bf(float f) {
    union { float f; uint32_t u; } v; v.f = f;
    return (uint16_t)((v.u + 0x7fffu + ((v.u >> 16) & 1u)) >> 16);
}
static __device__ __forceinline__ float bflo(uint32_t u) {
    union { uint32_t u; float f; } v; v.u = u << 16; return v.f;
}
static __device__ __forceinline__ float bfhi(uint32_t u) {
    union { uint32_t u; float f; } v; v.u = u & 0xffff0000u; return v.f;
}

// DPP butterfly add: x += lane-permuted x.  Pure VALU, no DS pipe.
// ctrl: 0xB1 = quad_perm ^1, 0x4E = quad_perm ^2, 0x141 = half_mirror (^7),
//       0x128 = row_ror:8 (^8 within 16).  span{1,2,7}=8 lanes; +^8 = 16.
template <int CTRL>
static __device__ __forceinline__ float dppadd(float x) {
    int p = __builtin_amdgcn_update_dpp(0, __float_as_int(x), CTRL, 0xf, 0xf, false);
    return x + __int_as_float(p);
}

// ---------------- slot init: slots = mu + exp(ls)*noise ----------------
__global__ __launch_bounds__(256) void kinit(const float* __restrict__ noise,
                                             const float* __restrict__ mu,
                                             const float* __restrict__ ls,
                                             float* __restrict__ slots) {
    int i = blockIdx.x * 256 + threadIdx.x;
    int base = i * 4;
    int d = base & 63;
    float4 nz = *(const float4*)(noise + base);
    float4 m  = *(const float4*)(mu + d);
    float4 s  = *(const float4*)(ls + d);
    float4 o;
    o.x = m.x + __expf(s.x) * nz.x;
    o.y = m.y + __expf(s.y) * nz.y;
    o.z = m.z + __expf(s.z) * nz.z;
    o.w = m.w + __expf(s.w) * nz.w;
    *(float4*)(slots + base) = o;
}

// ---------------- kM: M = (Wq^T @ Wk) / sqrt(D) ----------------
__global__ __launch_bounds__(256) void kM(const float* __restrict__ Wq,
                                          const float* __restrict__ Wk,
                                          float* __restrict__ M) {
    const int idx = blockIdx.x * 256 + threadIdx.x;  // 4096
    const int e = idx >> 6, f = idx & 63;
    float acc = 0.f;
#pragma unroll 8
    for (int d = 0; d < 64; ++d) acc += Wq[d * 64 + e] * Wk[d * 64 + f];
    M[idx] = acc * 0.125f;
}

// ---------------- k1: x = LN(inputs) -> bf16 (pure streaming) ----------
// 4 threads/row x 16 floats.  DPP 2-round reduce.  8192 blocks x 64 rows.
__global__ __launch_bounds__(256) void k1_ln(const float* __restrict__ inp,
                                             const float* __restrict__ lng,
                                             const float* __restrict__ lnb,
                                             uint16_t* __restrict__ xout) {
    const int t = threadIdx.x;
    const long row = (long)blockIdx.x * 64 + (t >> 2);
    const int c0 = (t & 3) * 16;

    const float* src = inp + row * 64 + c0;
    float x[16];
#pragma unroll
    for (int u = 0; u < 4; ++u) {
        float4 v4 = *(const float4*)(src + u * 4);
        x[u * 4 + 0] = v4.x; x[u * 4 + 1] = v4.y;
        x[u * 4 + 2] = v4.z; x[u * 4 + 3] = v4.w;
    }
    float s1 = 0.f, s2 = 0.f;
#pragma unroll
    for (int i = 0; i < 16; ++i) { s1 += x[i]; s2 += x[i] * x[i]; }
    s1 = dppadd<0xB1>(s1); s2 = dppadd<0xB1>(s2);
    s1 = dppadd<0x4E>(s1); s2 = dppadd<0x4E>(s2);
    const float mean = s1 * (1.0f / 64.0f);
    const float var = s2 * (1.0f / 64.0f) - mean * mean;
    const float rstd = rsqrtf(var + LN_EPSf);

    u16x8 o0, o1;
#pragma unroll
    for (int i = 0; i < 8; ++i) {
        o0[i] = f2bf((x[i] - mean) * rstd * lng[c0 + i] + lnb[c0 + i]);
        o1[i] = f2bf((x[8 + i] - mean) * rstd * lng[c0 + 8 + i] + lnb[c0 + 8 + i]);
    }
    uint16_t* dst = xout + row * 64 + c0;
    *(u16x8*)dst = o0;
    *(u16x8*)(dst + 8) = o1;
}

// ---------------- k2: attention pass over an N-chunk -------------------
// grid = B*PBn.  thread = (pg = t>>3 in [0,32), dc = t&7).  Reads ONLY x.
// logits via qk (= LN(slots)@M) dots; dc-lane reduce via DPP (no DS);
// softmax over K=8 per position; accumulate a*x and a.
// Tail: DPP ror8 then LDS copy-reduce.  Deterministic partials.
__global__ __launch_bounds__(256) void k2_attn(
    const uint16_t* __restrict__ xbf, const float* __restrict__ slots,
    const float* __restrict__ M, const float* __restrict__ lsg,
    const float* __restrict__ lsb, float* __restrict__ partials) {
    __shared__ float sraw[Kn * Dn];
    __shared__ float sln[Kn][68];
    __shared__ float qld[Kn][64];
    __shared__ float red[16 * 552];   // [copy][kk*68 + d], padded strides
    __shared__ float redas[16][8];

    const int t = threadIdx.x;
    const int b = blockIdx.x >> 3;
    const int part = blockIdx.x & 7;

    if (t < 128) *(float4*)(sraw + t * 4) = *(const float4*)(slots + b * 512 + t * 4);
    __syncthreads();

    // LN over slot rows (16 lanes/row); DPP reduce over ^1,^2,^7,^8
    if (t < 128) {
        const int row = t >> 4, l16 = t & 15;
        float4 v4 = *(const float4*)(sraw + row * 64 + l16 * 4);
        float s1 = v4.x + v4.y + v4.z + v4.w;
        float s2 = v4.x * v4.x + v4.y * v4.y + v4.z * v4.z + v4.w * v4.w;
        s1 = dppadd<0xB1>(s1); s2 = dppadd<0xB1>(s2);
        s1 = dppadd<0x4E>(s1); s2 = dppadd<0x4E>(s2);
        s1 = dppadd<0x141>(s1); s2 = dppadd<0x141>(s2);
        s1 = dppadd<0x128>(s1); s2 = dppadd<0x128>(s2);
        const float mean = s1 * (1.0f / 64.0f);
        const float var = s2 * (1.0f / 64.0f) - mean * mean;
        const float rstd = rsqrtf(var + LN_EPSf);
        const float xs[4] = {v4.x, v4.y, v4.z, v4.w};
#pragma unroll
        for (int i = 0; i < 4; ++i) {
            const int dcol = l16 * 4 + i;
            sln[row][dcol] = (xs[i] - mean) * rstd * lsg[dcol] + lsb[dcol];
        }
    }
    __syncthreads();

    // qk = sln @ M  (M already folded with 1/sqrt(D)); coalesced M-row reads
    {
        const int kk0 = t >> 6, kk1 = kk0 + 4;
        const int j = t & 63;
        float a0 = 0.f, a1 = 0.f;
#pragma unroll 8
        for (int e = 0; e < 64; ++e) {
            const float m = M[e * 64 + j];
            a0 += sln[kk0][e] * m;
            a1 += sln[kk1][e] * m;
        }
        qld[kk0][j] = a0;
        qld[kk1][j] = a1;
    }
    __syncthreads();

    const int dc = t & 7;
    const int pg = t >> 3;  // 0..31
    float qr[8][8];
#pragma unroll
    for (int kk = 0; kk < 8; ++kk) {
        float4 q0 = *(const float4*)&qld[kk][dc * 8];
        float4 q1 = *(const float4*)&qld[kk][dc * 8 + 4];
        qr[kk][0] = q0.x; qr[kk][1] = q0.y; qr[kk][2] = q0.z; qr[kk][3] = q0.w;
        qr[kk][4] = q1.x; qr[kk][5] = q1.y; qr[kk][6] = q1.z; qr[kk][7] = q1.w;
    }

    float upd[8][8];
    float asum[8];
#pragma unroll
    for (int kk = 0; kk < 8; ++kk) {
        asum[kk] = 0.f;
#pragma unroll
        for (int i = 0; i < 8; ++i) upd[kk][i] = 0.f;
    }

    const uint16_t* xbase = xbf + ((long)b * Nn + part * NCHUNKn) * 64 + dc * 8;

    uint4 xr = *(const uint4*)(xbase + (long)pg * 64);

    for (int it = 0; it < NCHUNKn / 32; ++it) {
        uint4 xn = xr;
        if (it < NCHUNKn / 32 - 1)
            xn = *(const uint4*)(xbase + (long)((it + 1) * 32 + pg) * 64);
        float xf[8];
        xf[0] = bflo(xr.x); xf[1] = bfhi(xr.x);
        xf[2] = bflo(xr.y); xf[3] = bfhi(xr.y);
        xf[4] = bflo(xr.z); xf[5] = bfhi(xr.z);
        xf[6] = bflo(xr.w); xf[7] = bfhi(xr.w);

        float lg[8];
#pragma unroll
        for (int kk = 0; kk < 8; ++kk) {
            float a = 0.f;
#pragma unroll
            for (int i = 0; i < 8; ++i) a += qr[kk][i] * xf[i];
            lg[kk] = a;
        }
        // reduce over the 8 dc lanes: DPP ^1, ^2, ^7 (span = all 8), no DS
#pragma unroll
        for (int kk = 0; kk < 8; ++kk) lg[kk] = dppadd<0xB1>(lg[kk]);
#pragma unroll
        for (int kk = 0; kk < 8; ++kk) lg[kk] = dppadd<0x4E>(lg[kk]);
#pragma unroll
        for (int kk = 0; kk < 8; ++kk) lg[kk] = dppadd<0x141>(lg[kk]);
        // softmax over the 8 slots (per position)
        float mx = lg[0];
#pragma unroll
        for (int kk = 1; kk < 8; ++kk) mx = fmaxf(mx, lg[kk]);
        float e[8];
        float es = 0.f;
#pragma unroll
        for (int kk = 0; kk < 8; ++kk) { e[kk] = __expf(lg[kk] - mx); es += e[kk]; }
        const float rinv = 1.0f / es;
#pragma unroll
        for (int kk = 0; kk < 8; ++kk) {
            const float a = e[kk] * rinv;
            asum[kk] += a;
#pragma unroll
            for (int i = 0; i < 8; ++i) upd[kk][i] += a * xf[i];
        }
        xr = xn;
    }

    // ---- tail: one DPP ror8 round (pairs pg within 16-lane rows) ----
#pragma unroll
    for (int kk = 0; kk < 8; ++kk) {
#pragma unroll
        for (int i = 0; i < 8; ++i) upd[kk][i] = dppadd<0x128>(upd[kk][i]);
        asum[kk] = dppadd<0x128>(asum[kk]);
    }
    // lanes with (l&8)==0 hold pg-pair sums: 16 copies -> LDS
    const int l = t & 63;
    const int wv = t >> 6;
    if ((l & 8) == 0) {
        const int copy = wv * 4 + (l >> 4);
        float* rb = red + copy * 552 + (l & 7) * 8;
#pragma unroll
        for (int kk = 0; kk < 8; ++kk) {
            float4 u0, u1;
            u0.x = upd[kk][0]; u0.y = upd[kk][1]; u0.z = upd[kk][2]; u0.w = upd[kk][3];
            u1.x = upd[kk][4]; u1.y = upd[kk][5]; u1.z = upd[kk][6]; u1.w = upd[kk][7];
            *(float4*)(rb + kk * 68) = u0;
            *(float4*)(rb + kk * 68 + 4) = u1;
        }
        if ((l & 15) == 0) {
            float4 a0, a1;
            a0.x = asum[0]; a0.y = asum[1]; a0.z = asum[2]; a0.w = asum[3];
            a1.x = asum[4]; a1.y = asum[5]; a1.z = asum[6]; a1.w = asum[7];
            *(float4*)&redas[copy][0] = a0;
            *(float4*)&redas[copy][4] = a1;
        }
    }
    __syncthreads();
    // ---- combine 16 copies, write partials ----
    float* pout = partials + (long)(b * PBn + part) * 520;
    if (t < 128) {
        const int kk = t >> 4, dq = t & 15;
        float4 acc = {0.f, 0.f, 0.f, 0.f};
#pragma unroll
        for (int c = 0; c < 16; ++c) {
            float4 v = *(const float4*)(red + c * 552 + kk * 68 + dq * 4);
            acc.x += v.x; acc.y += v.y; acc.z += v.z; acc.w += v.w;
        }
        *(float4*)(pout + kk * 64 + dq * 4) = acc;
    }
    if (t < 8) {
        float a = 0.f;
#pragma unroll
        for (int c = 0; c < 16; ++c) a += redas[c][t];
        pout[512 + t] = a;
    }
}

// ---------------- k3: partials -> updates (@Wv^T) + GRU + MLP ----------
// All dot-64 phases: 4 lanes/output x 16 floats (coalesced weight reads)
// + 2-round DPP reduce.
__global__ __launch_bounds__(256) void k3_update(
    const float* __restrict__ partials, const float* __restrict__ slots_in,
    const float* __restrict__ Wv,
    const float* __restrict__ wih, const float* __restrict__ whh,
    const float* __restrict__ bih, const float* __restrict__ bhh,
    const float* __restrict__ mg, const float* __restrict__ mb,
    const float* __restrict__ w1, const float* __restrict__ b1,
    const float* __restrict__ w2, const float* __restrict__ b2,
    float* __restrict__ slots_out) {
    __shared__ float axn[8][68];
    __shared__ float updf[8][68];
    __shared__ float sp[8][68];
    __shared__ float sn[8][68];
    __shared__ float hln[8][68];
    __shared__ float gi[8][196];
    __shared__ float gh[8][196];
    __shared__ float hid[8][260];
    __shared__ float asums[8];

    const int t = threadIdx.x;
    const int b = blockIdx.x;
    const float* pp = partials + (long)b * PBn * 520;

    if (t < 8) {
        float a = EPSf;
#pragma unroll
        for (int j = 0; j < PBn; ++j) a += pp[j * 520 + 512 + t];
        asums[t] = a;
    }
    if (t < 128) {
        float4 v = *(const float4*)(slots_in + b * 512 + t * 4);
        *(float4*)&sp[t >> 4][(t * 4) & 63] = v;
    }
    __syncthreads();
    if (t < 128) {
        const int kk = t >> 4, d = (t * 4) & 63;
        float4 o = {0.f, 0.f, 0.f, 0.f};
#pragma unroll
        for (int j = 0; j < PBn; ++j) {
            float4 a = *(const float4*)(pp + j * 520 + kk * 64 + d);
            o.x += a.x; o.y += a.y; o.z += a.z; o.w += a.w;
        }
        const float r = 1.0f / asums[kk];
        o.x *= r; o.y *= r; o.z *= r; o.w *= r;
        *(float4*)&axn[kk][d] = o;
    }
    __syncthreads();
    // updates = axn @ Wv^T   (512 outputs x 4 lanes)
    for (int w = t; w < 2048; w += 256) {
        const int j = w >> 2, h = w & 3;
        const int kk = j >> 6, d = j & 63;
        const float* wr = Wv + d * 64 + h * 16;
        float acc = 0.f;
#pragma unroll
        for (int u = 0; u < 4; ++u) {
            float4 wv4 = *(const float4*)(wr + u * 4);
            float4 av = *(const float4*)&axn[kk][h * 16 + u * 4];
            acc += wv4.x * av.x + wv4.y * av.y + wv4.z * av.z + wv4.w * av.w;
        }
        acc = dppadd<0xB1>(acc);
        acc = dppadd<0x4E>(acc);
        if (h == 0) updf[kk][d] = acc;
    }
    __syncthreads();
    // gi = updf @ wih^T + bih  (1536 outputs x 4 lanes)
    for (int w = t; w < 6144; w += 256) {
        const int o = w >> 2, h = w & 3;
        const int s = o / 192, jj = o - s * 192;
        const float* wr = wih + jj * 64 + h * 16;
        float acc = 0.f;
#pragma unroll
        for (int u = 0; u < 4; ++u) {
            float4 wv4 = *(const float4*)(wr + u * 4);
            float4 av = *(const float4*)&updf[s][h * 16 + u * 4];
            acc += wv4.x * av.x + wv4.y * av.y + wv4.z * av.z + wv4.w * av.w;
        }
        acc = dppadd<0xB1>(acc);
        acc = dppadd<0x4E>(acc);
        if (h == 0) gi[s][jj] = acc + bih[jj];
    }
    // gh = sp @ whh^T + bhh
    for (int w = t; w < 6144; w += 256) {
        const int o = w >> 2, h = w & 3;
        const int s = o / 192, jj = o - s * 192;
        const float* wr = whh + jj * 64 + h * 16;
        float acc = 0.f;
#pragma unroll
        for (int u = 0; u < 4; ++u) {
            float4 wv4 = *(const float4*)(wr + u * 4);
            float4 av = *(const float4*)&sp[s][h * 16 + u * 4];
            acc += wv4.x * av.x + wv4.y * av.y + wv4.z * av.z + wv4.w * av.w;
        }
        acc = dppadd<0xB1>(acc);
        acc = dppadd<0x4E>(acc);
        if (h == 0) gh[s][jj] = acc + bhh[jj];
    }
    __syncthreads();
    // gates
    for (int o = t; o < 512; o += 256) {
        const int s = o >> 6, d = o & 63;
        const float ir = gi[s][d], iz = gi[s][64 + d], in_ = gi[s][128 + d];
        const float hr = gh[s][d], hz = gh[s][64 + d], hn = gh[s][128 + d];
        const float r = 1.0f / (1.0f + __expf(-(ir + hr)));
        const float z = 1.0f / (1.0f + __expf(-(iz + hz)));
        const float n = tanhf(in_ + r * hn);
        sn[s][d] = (1.0f - z) * n + z * sp[s][d];
    }
    __syncthreads();
    // MLP layernorm (DPP reduce over 16 lanes)
    if (t < 128) {
        const int row = t >> 4, l16 = t & 15;
        float4 v4 = *(const float4*)&sn[row][l16 * 4];
        float s1 = v4.x + v4.y + v4.z + v4.w;
        float s2 = v4.x * v4.x + v4.y * v4.y + v4.z * v4.z + v4.w * v4.w;
        s1 = dppadd<0xB1>(s1); s2 = dppadd<0xB1>(s2);
        s1 = dppadd<0x4E>(s1); s2 = dppadd<0x4E>(s2);
        s1 = dppadd<0x141>(s1); s2 = dppadd<0x141>(s2);
        s1 = dppadd<0x128>(s1); s2 = dppadd<0x128>(s2);
        const float mean = s1 * (1.0f / 64.0f);
        const float var = s2 * (1.0f / 64.0f) - mean * mean;
        const float rstd = rsqrtf(var + LN_EPSf);
        const float xs[4] = {v4.x, v4.y, v4.z, v4.w};
#pragma unroll
        for (int i = 0; i < 4; ++i) {
            const int dcol = l16 * 4 + i;
            hln[row][dcol] = (xs[i] - mean) * rstd * mg[dcol] + mb[dcol];
        }
    }
    __syncthreads();
    // hid = relu(hln @ w1^T + b1)  (2048 outputs x 4 lanes)
    for (int w = t; w < 8192; w += 256) {
        const int o = w >> 2, h = w & 3;
        const int s = o >> 8, jj = o & 255;
        const float* wr = w1 + jj * 64 + h * 16;
        float acc = 0.f;
#pragma unroll
        for (int u = 0; u < 4; ++u) {
            float4 wv4 = *(const float4*)(wr + u * 4);
            float4 av = *(const float4*)&hln[s][h * 16 + u * 4];
            acc += wv4.x * av.x + wv4.y * av.y + wv4.z * av.z + wv4.w * av.w;
        }
        acc = dppadd<0xB1>(acc);
        acc = dppadd<0x4E>(acc);
        if (h == 0) hid[s][jj] = fmaxf(acc + b1[jj], 0.0f);
    }
    __syncthreads();
    // out = sn + hid @ w2^T + b2   (512 outputs x 4 lanes x dot-256)
    for (int w = t; w < 2048; w += 256) {
        const int o = w >> 2, h = w & 3;
        const int s = o >> 6, d = o & 63;
        const float* wr = w2 + d * 256 + h * 64;
        float acc = 0.f;
#pragma unroll
        for (int u = 0; u < 16; ++u) {
            float4 wv4 = *(const float4*)(wr + u * 4);
            float4 hv = *(const float4*)&hid[s][h * 64 + u * 4];
            acc += wv4.x * hv.x + wv4.y * hv.y + wv4.z * hv.z + wv4.w * hv.w;
        }
        acc = dppadd<0xB1>(acc);
        acc = dppadd<0x4E>(acc);
        if (h == 0) slots_out[(long)b * 512 + s * 64 + d] = sn[s][d] + acc + b2[d];
    }
}

extern "C" void kernel_launch(void* const* d_in, const int* in_sizes, int n_in,
                              void* d_out, int out_size, void* d_ws, size_t ws_size,
                              hipStream_t stream) {
    const float* inputs = (const float*)d_in[0];
    const float* noise = (const float*)d_in[1];
    const float* mu = (const float*)d_in[2];
    const float* ls = (const float*)d_in[3];
    const float* Wq = (const float*)d_in[4];
    const float* Wk = (const float*)d_in[5];
    const float* Wv = (const float*)d_in[6];
    const float* wih = (const float*)d_in[7];
    const float* whh = (const float*)d_in[8];
    const float* bih = (const float*)d_in[9];
    const float* bhh = (const float*)d_in[10];
    const float* lng = (const float*)d_in[11];
    const float* lnb = (const float*)d_in[12];
    const float* lsg = (const float*)d_in[13];
    const float* lsb = (const float*)d_in[14];
    const float* mg = (const float*)d_in[15];
    const float* mb = (const float*)d_in[16];
    const float* w1 = (const float*)d_in[17];
    const float* b1 = (const float*)d_in[18];
    const float* w2 = (const float*)d_in[19];
    const float* b2 = (const float*)d_in[20];

    char* ws = (char*)d_ws;
    float* slots = (float*)ws;                               // 256 KiB
    float* Mm = (float*)(ws + 262144);                       // 16 KiB
    uint16_t* xbf = (uint16_t*)(ws + 262144 + 16384);        // 64 MiB
    float* parts = (float*)(ws + 262144 + 16384 + (1 << 26));  // ~2.1 MiB

    kinit<<<64, 256, 0, stream>>>(noise, mu, ls, slots);
    kM<<<16, 256, 0, stream>>>(Wq, Wk, Mm);
    k1_ln<<<8192, 256, 0, stream>>>(inputs, lng, lnb, xbf);
    for (int it = 0; it < 3; ++it) {
        k2_attn<<<Bn * PBn, 256, 0, stream>>>(xbf, slots, Mm, lsg, lsb, parts);
        float* dst = (it == 2) ? (float*)d_out : slots;
        k3_update<<<Bn, 256, 0, stream>>>(parts, slots, Wv, wih, whh, bih, bhh,
                                          mg, mb, w1, b1, w2, b2, dst);
    }
}

// Round 5
// 210.391 us; speedup vs baseline: 2.7699x; 1.3048x over previous
//
#include <hip/hip_runtime.h>
#include <cstdint>

#define Bn 128
#define Nn 4096
#define Dn 64
#define Kn 8
#define PBn 8
#define NCHUNKn (Nn / PBn)
#define LN_EPSf 1e-5f
#define EPSf 1e-8f

typedef unsigned short u16x8 __attribute__((ext_vector_type(8)));

static __device__ __forceinline__ uint16_t f2bf(float f) {
    union { float f; uint32_t u; } v; v.f = f;
    return (uint16_t)((v.u + 0x7fffu + ((v.u >> 16) & 1u)) >> 16);
}
static __device__ __forceinline__ float bflo(uint32_t u) {
    union { uint32_t u; float f; } v; v.u = u << 16; return v.f;
}
static __device__ __forceinline__ float bfhi(uint32_t u) {
    union { uint32_t u; float f; } v; v.u = u & 0xffff0000u; return v.f;
}

// DPP butterfly add: x += lane-permuted x.  Pure VALU, no DS pipe.
// ctrl: 0xB1 = quad_perm ^1, 0x4E = quad_perm ^2, 0x141 = half_mirror (^7),
//       0x128 = row_ror:8 (^8 within 16).
template <int CTRL>
static __device__ __forceinline__ float dppadd(float x) {
    int p = __builtin_amdgcn_update_dpp(0, __float_as_int(x), CTRL, 0xf, 0xf, false);
    return x + __int_as_float(p);
}

// ---------------- slot init: slots = mu + exp(ls)*noise ----------------
__global__ __launch_bounds__(256) void kinit(const float* __restrict__ noise,
                                             const float* __restrict__ mu,
                                             const float* __restrict__ ls,
                                             float* __restrict__ slots) {
    int i = blockIdx.x * 256 + threadIdx.x;
    int base = i * 4;
    int d = base & 63;
    float4 nz = *(const float4*)(noise + base);
    float4 m  = *(const float4*)(mu + d);
    float4 s  = *(const float4*)(ls + d);
    float4 o;
    o.x = m.x + __expf(s.x) * nz.x;
    o.y = m.y + __expf(s.y) * nz.y;
    o.z = m.z + __expf(s.z) * nz.z;
    o.w = m.w + __expf(s.w) * nz.w;
    *(float4*)(slots + base) = o;
}

// ---------------- kM: M = (Wq^T @ Wk) / sqrt(D) ----------------
__global__ __launch_bounds__(256) void kM(const float* __restrict__ Wq,
                                          const float* __restrict__ Wk,
                                          float* __restrict__ M) {
    const int idx = blockIdx.x * 256 + threadIdx.x;  // 4096
    const int e = idx >> 6, f = idx & 63;
    float acc = 0.f;
#pragma unroll 8
    for (int d = 0; d < 64; ++d) acc += Wq[d * 64 + e] * Wk[d * 64 + f];
    M[idx] = acc * 0.125f;
}

// ---------------- k1: x = LN(inputs) -> bf16 (pure streaming) ----------
__global__ __launch_bounds__(256) void k1_ln(const float* __restrict__ inp,
                                             const float* __restrict__ lng,
                                             const float* __restrict__ lnb,
                                             uint16_t* __restrict__ xout) {
    const int t = threadIdx.x;
    const long row = (long)blockIdx.x * 64 + (t >> 2);
    const int c0 = (t & 3) * 16;

    const float* src = inp + row * 64 + c0;
    float x[16];
#pragma unroll
    for (int u = 0; u < 4; ++u) {
        float4 v4 = *(const float4*)(src + u * 4);
        x[u * 4 + 0] = v4.x; x[u * 4 + 1] = v4.y;
        x[u * 4 + 2] = v4.z; x[u * 4 + 3] = v4.w;
    }
    float s1 = 0.f, s2 = 0.f;
#pragma unroll
    for (int i = 0; i < 16; ++i) { s1 += x[i]; s2 += x[i] * x[i]; }
    s1 = dppadd<0xB1>(s1); s2 = dppadd<0xB1>(s2);
    s1 = dppadd<0x4E>(s1); s2 = dppadd<0x4E>(s2);
    const float mean = s1 * (1.0f / 64.0f);
    const float var = s2 * (1.0f / 64.0f) - mean * mean;
    const float rstd = rsqrtf(var + LN_EPSf);

    u16x8 o0, o1;
#pragma unroll
    for (int i = 0; i < 8; ++i) {
        o0[i] = f2bf((x[i] - mean) * rstd * lng[c0 + i] + lnb[c0 + i]);
        o1[i] = f2bf((x[8 + i] - mean) * rstd * lng[c0 + 8 + i] + lnb[c0 + 8 + i]);
    }
    uint16_t* dst = xout + row * 64 + c0;
    *(u16x8*)dst = o0;
    *(u16x8*)(dst + 8) = o1;
}

// ---------------- k2: attention pass over an N-chunk -------------------
__global__ __launch_bounds__(256) void k2_attn(
    const uint16_t* __restrict__ xbf, const float* __restrict__ slots,
    const float* __restrict__ M, const float* __restrict__ lsg,
    const float* __restrict__ lsb, float* __restrict__ partials) {
    __shared__ float sraw[Kn * Dn];
    __shared__ float sln[Kn][68];
    __shared__ float qld[Kn][64];
    __shared__ float red[16 * 552];   // [copy][kk*68 + d], padded strides
    __shared__ float redas[16][8];

    const int t = threadIdx.x;
    const int b = blockIdx.x >> 3;
    const int part = blockIdx.x & 7;

    if (t < 128) *(float4*)(sraw + t * 4) = *(const float4*)(slots + b * 512 + t * 4);
    __syncthreads();

    // LN over slot rows (16 lanes/row); DPP reduce over ^1,^2,^7,^8
    if (t < 128) {
        const int row = t >> 4, l16 = t & 15;
        float4 v4 = *(const float4*)(sraw + row * 64 + l16 * 4);
        float s1 = v4.x + v4.y + v4.z + v4.w;
        float s2 = v4.x * v4.x + v4.y * v4.y + v4.z * v4.z + v4.w * v4.w;
        s1 = dppadd<0xB1>(s1); s2 = dppadd<0xB1>(s2);
        s1 = dppadd<0x4E>(s1); s2 = dppadd<0x4E>(s2);
        s1 = dppadd<0x141>(s1); s2 = dppadd<0x141>(s2);
        s1 = dppadd<0x128>(s1); s2 = dppadd<0x128>(s2);
        const float mean = s1 * (1.0f / 64.0f);
        const float var = s2 * (1.0f / 64.0f) - mean * mean;
        const float rstd = rsqrtf(var + LN_EPSf);
        const float xs[4] = {v4.x, v4.y, v4.z, v4.w};
#pragma unroll
        for (int i = 0; i < 4; ++i) {
            const int dcol = l16 * 4 + i;
            sln[row][dcol] = (xs[i] - mean) * rstd * lsg[dcol] + lsb[dcol];
        }
    }
    __syncthreads();

    // qk = sln @ M  (M already folded with 1/sqrt(D))
    {
        const int kk0 = t >> 6, kk1 = kk0 + 4;
        const int j = t & 63;
        float a0 = 0.f, a1 = 0.f;
#pragma unroll 8
        for (int e = 0; e < 64; ++e) {
            const float m = M[e * 64 + j];
            a0 += sln[kk0][e] * m;
            a1 += sln[kk1][e] * m;
        }
        qld[kk0][j] = a0;
        qld[kk1][j] = a1;
    }
    __syncthreads();

    const int dc = t & 7;
    const int pg = t >> 3;  // 0..31
    float qr[8][8];
#pragma unroll
    for (int kk = 0; kk < 8; ++kk) {
        float4 q0 = *(const float4*)&qld[kk][dc * 8];
        float4 q1 = *(const float4*)&qld[kk][dc * 8 + 4];
        qr[kk][0] = q0.x; qr[kk][1] = q0.y; qr[kk][2] = q0.z; qr[kk][3] = q0.w;
        qr[kk][4] = q1.x; qr[kk][5] = q1.y; qr[kk][6] = q1.z; qr[kk][7] = q1.w;
    }

    float upd[8][8];
    float asum[8];
#pragma unroll
    for (int kk = 0; kk < 8; ++kk) {
        asum[kk] = 0.f;
#pragma unroll
        for (int i = 0; i < 8; ++i) upd[kk][i] = 0.f;
    }

    const uint16_t* xbase = xbf + ((long)b * Nn + part * NCHUNKn) * 64 + dc * 8;

    uint4 xr = *(const uint4*)(xbase + (long)pg * 64);

    for (int it = 0; it < NCHUNKn / 32; ++it) {
        uint4 xn = xr;
        if (it < NCHUNKn / 32 - 1)
            xn = *(const uint4*)(xbase + (long)((it + 1) * 32 + pg) * 64);
        float xf[8];
        xf[0] = bflo(xr.x); xf[1] = bfhi(xr.x);
        xf[2] = bflo(xr.y); xf[3] = bfhi(xr.y);
        xf[4] = bflo(xr.z); xf[5] = bfhi(xr.z);
        xf[6] = bflo(xr.w); xf[7] = bfhi(xr.w);

        float lg[8];
#pragma unroll
        for (int kk = 0; kk < 8; ++kk) {
            float a = 0.f;
#pragma unroll
            for (int i = 0; i < 8; ++i) a += qr[kk][i] * xf[i];
            lg[kk] = a;
        }
#pragma unroll
        for (int kk = 0; kk < 8; ++kk) lg[kk] = dppadd<0xB1>(lg[kk]);
#pragma unroll
        for (int kk = 0; kk < 8; ++kk) lg[kk] = dppadd<0x4E>(lg[kk]);
#pragma unroll
        for (int kk = 0; kk < 8; ++kk) lg[kk] = dppadd<0x141>(lg[kk]);
        float mx = lg[0];
#pragma unroll
        for (int kk = 1; kk < 8; ++kk) mx = fmaxf(mx, lg[kk]);
        float e[8];
        float es = 0.f;
#pragma unroll
        for (int kk = 0; kk < 8; ++kk) { e[kk] = __expf(lg[kk] - mx); es += e[kk]; }
        const float rinv = 1.0f / es;
#pragma unroll
        for (int kk = 0; kk < 8; ++kk) {
            const float a = e[kk] * rinv;
            asum[kk] += a;
#pragma unroll
            for (int i = 0; i < 8; ++i) upd[kk][i] += a * xf[i];
        }
        xr = xn;
    }

    // ---- tail: one DPP ror8 round (pairs pg within 16-lane rows) ----
#pragma unroll
    for (int kk = 0; kk < 8; ++kk) {
#pragma unroll
        for (int i = 0; i < 8; ++i) upd[kk][i] = dppadd<0x128>(upd[kk][i]);
        asum[kk] = dppadd<0x128>(asum[kk]);
    }
    const int l = t & 63;
    const int wv = t >> 6;
    if ((l & 8) == 0) {
        const int copy = wv * 4 + (l >> 4);
        float* rb = red + copy * 552 + (l & 7) * 8;
#pragma unroll
        for (int kk = 0; kk < 8; ++kk) {
            float4 u0, u1;
            u0.x = upd[kk][0]; u0.y = upd[kk][1]; u0.z = upd[kk][2]; u0.w = upd[kk][3];
            u1.x = upd[kk][4]; u1.y = upd[kk][5]; u1.z = upd[kk][6]; u1.w = upd[kk][7];
            *(float4*)(rb + kk * 68) = u0;
            *(float4*)(rb + kk * 68 + 4) = u1;
        }
        if ((l & 15) == 0) {
            float4 a0, a1;
            a0.x = asum[0]; a0.y = asum[1]; a0.z = asum[2]; a0.w = asum[3];
            a1.x = asum[4]; a1.y = asum[5]; a1.z = asum[6]; a1.w = asum[7];
            *(float4*)&redas[copy][0] = a0;
            *(float4*)&redas[copy][4] = a1;
        }
    }
    __syncthreads();
    float* pout = partials + (long)(b * PBn + part) * 520;
    if (t < 128) {
        const int kk = t >> 4, dq = t & 15;
        float4 acc = {0.f, 0.f, 0.f, 0.f};
#pragma unroll
        for (int c = 0; c < 16; ++c) {
            float4 v = *(const float4*)(red + c * 552 + kk * 68 + dq * 4);
            acc.x += v.x; acc.y += v.y; acc.z += v.z; acc.w += v.w;
        }
        *(float4*)(pout + kk * 64 + dq * 4) = acc;
    }
    if (t < 8) {
        float a = 0.f;
#pragma unroll
        for (int c = 0; c < 16; ++c) a += redas[c][t];
        pout[512 + t] = a;
    }
}

// ---------------- k3: per-(batch,slot) update: Wv + GRU + MLP ----------
// grid = B*K = 1024 blocks (4/CU).  One slot per block; all matvec phases
// are 4-lane dots with coalesced weight reads + DPP quad reduce.
__global__ __launch_bounds__(256) void k3_update(
    const float* __restrict__ partials, const float* __restrict__ slots_in,
    const float* __restrict__ Wv,
    const float* __restrict__ wih, const float* __restrict__ whh,
    const float* __restrict__ bih, const float* __restrict__ bhh,
    const float* __restrict__ mg, const float* __restrict__ mb,
    const float* __restrict__ w1, const float* __restrict__ b1,
    const float* __restrict__ w2, const float* __restrict__ b2,
    float* __restrict__ slots_out) {
    __shared__ float axn[64];
    __shared__ float updf[64];
    __shared__ float sp[64];
    __shared__ float gi[192];
    __shared__ float gh[192];
    __shared__ float sn[64];
    __shared__ float hln[64];
    __shared__ float hid[256];

    const int t = threadIdx.x;
    const int b = blockIdx.x >> 3;
    const int s = blockIdx.x & 7;
    const float* pp = partials + (long)b * PBn * 520;

    // asum (computed redundantly by all threads; broadcast loads)
    float asum = EPSf;
#pragma unroll
    for (int j = 0; j < PBn; ++j) asum += pp[j * 520 + 512 + s];
    const float rasum = 1.0f / asum;

    if (t < 64) {
        float a = 0.f;
#pragma unroll
        for (int j = 0; j < PBn; ++j) a += pp[j * 520 + s * 64 + t];
        axn[t] = a * rasum;
    } else if (t < 80) {
        const int i = t - 64;
        *(float4*)&sp[i * 4] = *(const float4*)(slots_in + b * 512 + s * 64 + i * 4);
    }
    __syncthreads();

    // updates = axn @ Wv^T  (64 outputs x 4 lanes = 1 round)
    {
        const int d = t >> 2, h = t & 3;
        const float* wr = Wv + d * 64 + h * 16;
        float acc = 0.f;
#pragma unroll
        for (int u = 0; u < 4; ++u) {
            float4 w4 = *(const float4*)(wr + u * 4);
            float4 a4 = *(const float4*)&axn[h * 16 + u * 4];
            acc += w4.x * a4.x + w4.y * a4.y + w4.z * a4.z + w4.w * a4.w;
        }
        acc = dppadd<0xB1>(acc);
        acc = dppadd<0x4E>(acc);
        if (h == 0) updf[d] = acc;
    }
    __syncthreads();

    // gi = updf @ wih^T + bih  (192 outputs x 4 lanes = 3 rounds)
    for (int w = t; w < 768; w += 256) {
        const int j = w >> 2, h = w & 3;
        const float* wr = wih + j * 64 + h * 16;
        float acc = 0.f;
#pragma unroll
        for (int u = 0; u < 4; ++u) {
            float4 w4 = *(const float4*)(wr + u * 4);
            float4 a4 = *(const float4*)&updf[h * 16 + u * 4];
            acc += w4.x * a4.x + w4.y * a4.y + w4.z * a4.z + w4.w * a4.w;
        }
        acc = dppadd<0xB1>(acc);
        acc = dppadd<0x4E>(acc);
        if (h == 0) gi[j] = acc + bih[j];
    }
    // gh = sp @ whh^T + bhh
    for (int w = t; w < 768; w += 256) {
        const int j = w >> 2, h = w & 3;
        const float* wr = whh + j * 64 + h * 16;
        float acc = 0.f;
#pragma unroll
        for (int u = 0; u < 4; ++u) {
            float4 w4 = *(const float4*)(wr + u * 4);
            float4 a4 = *(const float4*)&sp[h * 16 + u * 4];
            acc += w4.x * a4.x + w4.y * a4.y + w4.z * a4.z + w4.w * a4.w;
        }
        acc = dppadd<0xB1>(acc);
        acc = dppadd<0x4E>(acc);
        if (h == 0) gh[j] = acc + bhh[j];
    }
    __syncthreads();

    // gates
    if (t < 64) {
        const float ir = gi[t], iz = gi[64 + t], in_ = gi[128 + t];
        const float hr = gh[t], hz = gh[64 + t], hn = gh[128 + t];
        const float r = 1.0f / (1.0f + __expf(-(ir + hr)));
        const float z = 1.0f / (1.0f + __expf(-(iz + hz)));
        const float n = tanhf(in_ + r * hn);
        sn[t] = (1.0f - z) * n + z * sp[t];
    }
    __syncthreads();

    // MLP layernorm (16 lanes, DPP reduce)
    if (t < 16) {
        float4 v4 = *(const float4*)&sn[t * 4];
        float s1 = v4.x + v4.y + v4.z + v4.w;
        float s2 = v4.x * v4.x + v4.y * v4.y + v4.z * v4.z + v4.w * v4.w;
        s1 = dppadd<0xB1>(s1); s2 = dppadd<0xB1>(s2);
        s1 = dppadd<0x4E>(s1); s2 = dppadd<0x4E>(s2);
        s1 = dppadd<0x141>(s1); s2 = dppadd<0x141>(s2);
        s1 = dppadd<0x128>(s1); s2 = dppadd<0x128>(s2);
        const float mean = s1 * (1.0f / 64.0f);
        const float var = s2 * (1.0f / 64.0f) - mean * mean;
        const float rstd = rsqrtf(var + LN_EPSf);
        const float xs[4] = {v4.x, v4.y, v4.z, v4.w};
#pragma unroll
        for (int i = 0; i < 4; ++i) {
            const int dcol = t * 4 + i;
            hln[dcol] = (xs[i] - mean) * rstd * mg[dcol] + mb[dcol];
        }
    }
    __syncthreads();

    // hid = relu(hln @ w1^T + b1)  (256 outputs x 4 lanes = 4 rounds)
    for (int w = t; w < 1024; w += 256) {
        const int j = w >> 2, h = w & 3;
        const float* wr = w1 + j * 64 + h * 16;
        float acc = 0.f;
#pragma unroll
        for (int u = 0; u < 4; ++u) {
            float4 w4 = *(const float4*)(wr + u * 4);
            float4 a4 = *(const float4*)&hln[h * 16 + u * 4];
            acc += w4.x * a4.x + w4.y * a4.y + w4.z * a4.z + w4.w * a4.w;
        }
        acc = dppadd<0xB1>(acc);
        acc = dppadd<0x4E>(acc);
        if (h == 0) hid[j] = fmaxf(acc + b1[j], 0.0f);
    }
    __syncthreads();

    // out = sn + hid @ w2^T + b2  (64 outputs x 4 lanes x dot-256 = 1 round)
    {
        const int d = t >> 2, h = t & 3;
        const float* wr = w2 + d * 256 + h * 64;
        float acc = 0.f;
#pragma unroll
        for (int u = 0; u < 16; ++u) {
            float4 w4 = *(const float4*)(wr + u * 4);
            float4 h4 = *(const float4*)&hid[h * 64 + u * 4];
            acc += w4.x * h4.x + w4.y * h4.y + w4.z * h4.z + w4.w * h4.w;
        }
        acc = dppadd<0xB1>(acc);
        acc = dppadd<0x4E>(acc);
        if (h == 0) slots_out[(long)b * 512 + s * 64 + d] = sn[d] + acc + b2[d];
    }
}

extern "C" void kernel_launch(void* const* d_in, const int* in_sizes, int n_in,
                              void* d_out, int out_size, void* d_ws, size_t ws_size,
                              hipStream_t stream) {
    const float* inputs = (const float*)d_in[0];
    const float* noise = (const float*)d_in[1];
    const float* mu = (const float*)d_in[2];
    const float* ls = (const float*)d_in[3];
    const float* Wq = (const float*)d_in[4];
    const float* Wk = (const float*)d_in[5];
    const float* Wv = (const float*)d_in[6];
    const float* wih = (const float*)d_in[7];
    const float* whh = (const float*)d_in[8];
    const float* bih = (const float*)d_in[9];
    const float* bhh = (const float*)d_in[10];
    const float* lng = (const float*)d_in[11];
    const float* lnb = (const float*)d_in[12];
    const float* lsg = (const float*)d_in[13];
    const float* lsb = (const float*)d_in[14];
    const float* mg = (const float*)d_in[15];
    const float* mb = (const float*)d_in[16];
    const float* w1 = (const float*)d_in[17];
    const float* b1 = (const float*)d_in[18];
    const float* w2 = (const float*)d_in[19];
    const float* b2 = (const float*)d_in[20];

    char* ws = (char*)d_ws;
    float* slots = (float*)ws;                               // 256 KiB
    float* Mm = (float*)(ws + 262144);                       // 16 KiB
    uint16_t* xbf = (uint16_t*)(ws + 262144 + 16384);        // 64 MiB
    float* parts = (float*)(ws + 262144 + 16384 + (1 << 26));  // ~2.1 MiB

    kinit<<<64, 256, 0, stream>>>(noise, mu, ls, slots);
    kM<<<16, 256, 0, stream>>>(Wq, Wk, Mm);
    k1_ln<<<8192, 256, 0, stream>>>(inputs, lng, lnb, xbf);
    for (int it = 0; it < 3; ++it) {
        k2_attn<<<Bn * PBn, 256, 0, stream>>>(xbf, slots, Mm, lsg, lsb, parts);
        float* dst = (it == 2) ? (float*)d_out : slots;
        k3_update<<<Bn * Kn, 256, 0, stream>>>(parts, slots, Wv, wih, whh, bih, bhh,
                                               mg, mb, w1, b1, w2, b2, dst);
    }
}